// Round 2
// baseline (968.858 us; speedup 1.0000x reference)
//
#include <hip/hip_runtime.h>

// ============================================================================
// Encoder (conv/pool) -> degenerate NTM step (zero-state collapse) -> Decoder.
// Round 2: fix LDS weight-slot collision in conv64_kernel (c2=62/63 overflowed
// the 768-float per-chunk region -> cross-chunk write races corrupting output
// channels 0,1,62,63 of conv1/conv3/conv4). Plain stride-12 packing now.
// Still fp64 accumulation everywhere to establish the accuracy noise floor.
// ============================================================================

// ---- workspace layout (bytes) ----
static const size_t OFF0   = 0;            // conv0+pool out (64,64,32,32) f32   16MB
static const size_t OFF1   = 16777216;     // conv1 out      (64,64,32,32) f32   16MB
static const size_t OFF2   = 33554432;     // pool1 out      (64,64,16,16) f32    4MB
static const size_t OFF3   = 37748736;     // x = enc out    (64,256)      f32   64KB
static const size_t OFF_H  = 37814272;     // h              (64,256)      f32   64KB
static const size_t OFF_RV = 37879808;     // rv             (64,3)        f64  1.5KB
static const size_t OFF_RS = 37881344;     // rowsums        (3,256)       f64    6KB
static const size_t OFF_N  = 37887488;     // ntm out        (64,256)      f32   64KB
static const size_t OFF4   = 37953024;     // conv2 out      (64,64,16,16) f32    4MB
static const size_t OFF5   = 42147328;     // conv3 out      (64,64,32,32) f32   16MB
static const size_t OFF_W1 = 58924544;     // wT conv1 (ci,co,9) f32            144KB
static const size_t OFF_W3 = 59072000;     // wT conv3
static const size_t OFF_W4 = 59219456;     // wT conv4                 end ~59.4MB

// ---- transpose (co,ci,9) -> (ci,co,9) for LDS-friendly staging ----
__global__ void transpose_w_kernel(const float* __restrict__ w, float* __restrict__ wT) {
    int s = blockIdx.x * 256 + threadIdx.x;
    if (s >= 64 * 64 * 9) return;
    int co = s / 576; int rem = s % 576; int ci = rem / 9; int t = rem % 9;
    wT[(ci * 64 + co) * 9 + t] = w[s];
}

// ---- fused conv0 (1->64, 3x3 SAME, relu) + avgpool2 : in (64,1,64,64) -> out (64,64,32,32) ----
__global__ __launch_bounds__(256) void conv0_pool_kernel(
    const float* __restrict__ in, const float* __restrict__ w,
    const float* __restrict__ bias, float* __restrict__ out)
{
    int idx = blockIdx.x * 256 + threadIdx.x;           // 4,194,304 total
    int x = idx & 31, y = (idx >> 5) & 31, co = (idx >> 10) & 63, b = idx >> 16;
    double w9[9];
#pragma unroll
    for (int t = 0; t < 9; ++t) w9[t] = (double)w[co * 9 + t];
    double bv = (double)bias[co];
    const float* ip = in + (size_t)b * 4096;
    double p[4][4];
#pragma unroll
    for (int r = 0; r < 4; ++r) {
        int gy = 2 * y - 1 + r;
#pragma unroll
        for (int c = 0; c < 4; ++c) {
            int gx = 2 * x - 1 + c;
            float v = 0.f;
            if ((unsigned)gy < 64u && (unsigned)gx < 64u) v = ip[gy * 64 + gx];
            p[r][c] = (double)v;
        }
    }
    double s4 = 0.0;
#pragma unroll
    for (int dy = 0; dy < 2; ++dy)
#pragma unroll
        for (int dx = 0; dx < 2; ++dx) {
            double a = bv;
#pragma unroll
            for (int ky = 0; ky < 3; ++ky)
#pragma unroll
                for (int kx = 0; kx < 3; ++kx)
                    a = fma(w9[ky * 3 + kx], p[dy + ky][dx + kx], a);
            float cf = (float)a;            // reference rounds conv out to f32
            cf = fmaxf(cf, 0.f);            // relu
            s4 += (double)cf;
        }
    out[idx] = (float)(s4 * 0.25);
}

// ---- generic 64->64 3x3 SAME conv + relu, optional fused 2x upsample of src ----
// src (B,64,H>>UP,H>>UP) logical-upsampled to (H,H); out (B,64,H,H)
template <int UP>
__global__ __launch_bounds__(256, 2) void conv64_kernel(
    const float* __restrict__ src, const float* __restrict__ wT,
    const float* __restrict__ bias, float* __restrict__ out, int H)
{
    const int srcH = H >> UP;
    const int tpr = H >> 3;                 // tiles per row (8x8 tiles)
    int blk = blockIdx.x;
    int b = blk / (tpr * tpr);
    int tt = blk % (tpr * tpr);
    int y0 = (tt / tpr) * 8, x0 = (tt % tpr) * 8;
    const int tid = threadIdx.x;
    const int co = tid & 63;
    const int grp = tid >> 6;               // wave id; each wave owns 2 output rows

    __shared__ float sIn[7680];             // [64ci][10r][12c-padded]
    __shared__ float sW[6144];              // 8ci x 64co x 12 (compact, collision-free)

    // stage input tile with halo (zero-padded SAME), fused upsample via >>UP
    for (int k = tid; k < 6400; k += 256) {
        int ci = k / 100; int r = (k / 10) % 10; int c = k % 10;
        int gy = y0 - 1 + r, gx = x0 - 1 + c;
        float v = 0.f;
        if ((unsigned)gy < (unsigned)H && (unsigned)gx < (unsigned)H)
            v = src[((size_t)(b * 64 + ci) * srcH + (gy >> UP)) * srcH + (gx >> UP)];
        sIn[(ci * 10 + r) * 12 + c] = v;
    }

    double acc[16];
#pragma unroll
    for (int i = 0; i < 16; ++i) acc[i] = 0.0;
    const int rbase = grp * 2;

    for (int ci0 = 0; ci0 < 64; ci0 += 8) {
        __syncthreads();                    // also covers sIn staging on iter 0
        for (int k = tid; k < 4608; k += 256) {
            int cip = k / 576; int rem = k % 576; int c2 = rem / 9; int t = rem % 9;
            sW[cip * 768 + c2 * 12 + t] =
                wT[((size_t)(ci0 + cip) * 64 + c2) * 9 + t];
        }
        __syncthreads();
#pragma unroll
        for (int cip = 0; cip < 8; ++cip) {
            int ci = ci0 + cip;
            const float4* rp = (const float4*)&sIn[(ci * 10 + rbase) * 12];
            double dr[4][12];
#pragma unroll
            for (int r = 0; r < 4; ++r) {   // broadcast reads (wave-uniform addr)
                float4 a = rp[r * 3 + 0]; float4 b4 = rp[r * 3 + 1]; float4 c4 = rp[r * 3 + 2];
                dr[r][0] = a.x;  dr[r][1] = a.y;  dr[r][2] = a.z;  dr[r][3] = a.w;
                dr[r][4] = b4.x; dr[r][5] = b4.y; dr[r][6] = b4.z; dr[r][7] = b4.w;
                dr[r][8] = c4.x; dr[r][9] = c4.y; dr[r][10] = c4.z; dr[r][11] = c4.w;
            }
            const float4* wp = (const float4*)&sW[cip * 768 + co * 12];
            float4 w0 = wp[0], w1 = wp[1], w2 = wp[2];
            double dw[9] = { w0.x, w0.y, w0.z, w0.w, w1.x, w1.y, w1.z, w1.w, w2.x };
#pragma unroll
            for (int ky = 0; ky < 3; ++ky) {
#pragma unroll
                for (int kx = 0; kx < 3; ++kx) {
                    double wv = dw[ky * 3 + kx];
#pragma unroll
                    for (int px = 0; px < 8; ++px) {
                        acc[px]     = fma(wv, dr[ky][px + kx],     acc[px]);
                        acc[8 + px] = fma(wv, dr[ky + 1][px + kx], acc[8 + px]);
                    }
                }
            }
        }
    }
    double bv = (double)bias[co];
#pragma unroll
    for (int pyl = 0; pyl < 2; ++pyl)
#pragma unroll
        for (int px = 0; px < 8; ++px) {
            float v = (float)(acc[pyl * 8 + px] + bv);
            v = fmaxf(v, 0.f);
            int y = y0 + rbase + pyl, x = x0 + px;
            out[((size_t)(b * 64 + co) * H + y) * H + x] = v;
        }
}

// ---- avgpool2: (64,64,2Ho,2Ho) -> (64,64,Ho,Ho) ----
__global__ void pool_kernel(const float* __restrict__ in, float* __restrict__ out, int Ho)
{
    int idx = blockIdx.x * 256 + threadIdx.x;
    int n = 64 * 64 * Ho * Ho;
    if (idx >= n) return;
    int x = idx % Ho; int y = (idx / Ho) % Ho; int p = idx / (Ho * Ho);
    int Hi = 2 * Ho;
    const float* ip = in + (size_t)p * Hi * Hi;
    double s = (double)ip[(2 * y) * Hi + 2 * x] + (double)ip[(2 * y) * Hi + 2 * x + 1]
             + (double)ip[(2 * y + 1) * Hi + 2 * x] + (double)ip[(2 * y + 1) * Hi + 2 * x + 1];
    out[idx] = (float)(s * 0.25);
}

// ---- enc conv: 64->1, 16x16, relu -> x (64,256) ----
__global__ __launch_bounds__(256) void enc_kernel(
    const float* __restrict__ in, const float* __restrict__ w,
    const float* __restrict__ bias, float* __restrict__ xout)
{
    int b = blockIdx.x; int tid = threadIdx.x;
    int y = tid >> 4, x = tid & 15;
    __shared__ float sE[8192];
    double acc = 0.0;
    for (int ch = 0; ch < 2; ++ch) {
        __syncthreads();
        for (int k = tid; k < 8192; k += 256) sE[k] = in[(size_t)b * 16384 + ch * 8192 + k];
        __syncthreads();
        for (int cip = 0; cip < 32; ++cip) {
            int ci = ch * 32 + cip;
#pragma unroll
            for (int ky = 0; ky < 3; ++ky) {
                int gy = y + ky - 1;
                if ((unsigned)gy >= 16u) continue;
#pragma unroll
                for (int kx = 0; kx < 3; ++kx) {
                    int gx = x + kx - 1;
                    if ((unsigned)gx >= 16u) continue;
                    acc = fma((double)w[ci * 9 + ky * 3 + kx],
                              (double)sE[cip * 256 + gy * 16 + gx], acc);
                }
            }
        }
    }
    float v = (float)(acc + (double)bias[0]);
    xout[b * 256 + tid] = fmaxf(v, 0.f);
}

// ---- LSTM (zero state): h = sig(zo)*tanh(sig(zi)*tanh(zg)), z = x @ Wx[:256] + b ----
__global__ __launch_bounds__(256) void lstm_kernel(
    const float* __restrict__ x, const float* __restrict__ wx,
    const float* __restrict__ bl, float* __restrict__ h)
{
    int b = blockIdx.x, j = threadIdx.x;
    __shared__ float sx[256];
    sx[j] = x[b * 256 + j];
    __syncthreads();
    double zi = 0, zg = 0, zo = 0;
    for (int d = 0; d < 256; ++d) {
        double xv = (double)sx[d];
        const float* row = wx + (size_t)d * 1024;
        zi = fma(xv, (double)row[j], zi);
        zg = fma(xv, (double)row[512 + j], zg);
        zo = fma(xv, (double)row[768 + j], zo);
    }
    float zif = (float)(zi + (double)bl[j]);
    float zgf = (float)(zg + (double)bl[512 + j]);
    float zof = (float)(zo + (double)bl[768 + j]);
    double c = (1.0 / (1.0 + exp(-(double)zif))) * tanh((double)zgf);
    float cf = (float)c;
    double hh = (1.0 / (1.0 + exp(-(double)zof))) * tanh((double)cf);
    h[b * 256 + j] = (float)hh;
}

// ---- rowsums of w_out reads-block: rs[r][m] = sum_d w_out[256+r*256+d, m] ----
__global__ void rowsum_kernel(const float* __restrict__ w_out, double* __restrict__ rs)
{
    int r = blockIdx.x, m = threadIdx.x;
    double s = 0;
    for (int d = 0; d < 256; ++d) s += (double)w_out[(size_t)(256 + r * 256 + d) * 256 + m];
    rs[r * 256 + m] = s;
}

// ---- read-head scalar: rv[b,r] = 64e-6 * q/(64q+1e-8), q=(1/64+1e-16)^gamma ----
__global__ __launch_bounds__(256) void gamma_kernel(
    const float* __restrict__ h, const float* __restrict__ w_param,
    const float* __restrict__ b_param, double* __restrict__ rv)
{
    int b = blockIdx.x, t = threadIdx.x;
    __shared__ double sp[3][256];
    float hv = h[b * 256 + t];
#pragma unroll
    for (int r = 0; r < 3; ++r)
        sp[r][t] = (double)hv * (double)w_param[(size_t)t * 3108 + r * 262 + 261];
    __syncthreads();
    if (t < 3) {
        double s = 0;
        for (int d = 0; d < 256; ++d) s += sp[t][d];
        float pf = (float)(s + (double)b_param[t * 262 + 261]);
        pf = fminf(fmaxf(pf, -20.f), 20.f);                 // CLIP
        double gamma = log1p(exp((double)pf)) + 1.0;        // softplus + 1
        double q = pow(0.015625 + 1e-16, gamma);
        double wv = q / (64.0 * q + 1e-8);
        rv[b * 3 + t] = wv * 64.0 * 1e-6;
    }
}

// ---- ntm out: clip(h@w_out[:256] + b_out + sum_r rv_r*rs_r, +-20) ----
__global__ __launch_bounds__(256) void ntmout_kernel(
    const float* __restrict__ h, const float* __restrict__ w_out,
    const float* __restrict__ b_out, const double* __restrict__ rv,
    const double* __restrict__ rs, float* __restrict__ out)
{
    int b = blockIdx.x, m = threadIdx.x;
    __shared__ float sh[256];
    __shared__ double srv[3];
    sh[m] = h[b * 256 + m];
    if (m < 3) srv[m] = rv[b * 3 + m];
    __syncthreads();
    double acc = 0;
    for (int d = 0; d < 256; ++d)
        acc = fma((double)sh[d], (double)w_out[(size_t)d * 256 + m], acc);
    acc += (double)b_out[m];
#pragma unroll
    for (int r = 0; r < 3; ++r) acc += srv[r] * rs[r * 256 + m];
    acc = fmin(fmax(acc, -20.0), 20.0);
    out[b * 256 + m] = (float)acc;
}

// ---- 1->64 3x3 SAME conv + relu (used for conv2, H=16) ----
__global__ void conv1to64_kernel(
    const float* __restrict__ in, const float* __restrict__ w,
    const float* __restrict__ bias, float* __restrict__ out, int H)
{
    int idx = blockIdx.x * 256 + threadIdx.x;
    int HH = H * H;
    int x = idx % H; int y = (idx / H) % H; int co = (idx / HH) & 63; int b = idx / (HH * 64);
    double acc = (double)bias[co];
    const float* ip = in + (size_t)b * HH;
#pragma unroll
    for (int ky = 0; ky < 3; ++ky) {
        int gy = y + ky - 1;
        if ((unsigned)gy >= (unsigned)H) continue;
#pragma unroll
        for (int kx = 0; kx < 3; ++kx) {
            int gx = x + kx - 1;
            if ((unsigned)gx >= (unsigned)H) continue;
            acc = fma((double)w[co * 9 + ky * 3 + kx], (double)ip[gy * H + gx], acc);
        }
    }
    float v = (float)acc;
    out[idx] = fmaxf(v, 0.f);
}

extern "C" void kernel_launch(void* const* d_in, const int* in_sizes, int n_in,
                              void* d_out, int out_size, void* d_ws, size_t ws_size,
                              hipStream_t stream)
{
    const float* inputs   = (const float*)d_in[0];
    const float* w_conv0  = (const float*)d_in[1];
    const float* b_conv0  = (const float*)d_in[2];
    const float* w_conv1  = (const float*)d_in[3];
    const float* b_conv1  = (const float*)d_in[4];
    const float* w_enc    = (const float*)d_in[5];
    const float* b_enc    = (const float*)d_in[6];
    const float* w_conv2  = (const float*)d_in[7];
    const float* b_conv2  = (const float*)d_in[8];
    const float* w_conv3  = (const float*)d_in[9];
    const float* b_conv3  = (const float*)d_in[10];
    const float* w_conv4  = (const float*)d_in[11];
    const float* b_conv4  = (const float*)d_in[12];
    const float* w_lstm_x = (const float*)d_in[13];
    // d_in[14] = w_lstm_h : dead (h0 == 0)
    const float* b_lstm   = (const float*)d_in[15];
    const float* w_param  = (const float*)d_in[16];
    const float* b_param  = (const float*)d_in[17];
    const float* w_out_   = (const float*)d_in[18];
    const float* b_out_   = (const float*)d_in[19];

    char* ws = (char*)d_ws;
    float*  t0  = (float*)(ws + OFF0);
    float*  t1  = (float*)(ws + OFF1);
    float*  t2  = (float*)(ws + OFF2);
    float*  xE  = (float*)(ws + OFF3);
    float*  h   = (float*)(ws + OFF_H);
    double* rv  = (double*)(ws + OFF_RV);
    double* rs  = (double*)(ws + OFF_RS);
    float*  ntm = (float*)(ws + OFF_N);
    float*  t4  = (float*)(ws + OFF4);
    float*  t5  = (float*)(ws + OFF5);
    float*  wT1 = (float*)(ws + OFF_W1);
    float*  wT3 = (float*)(ws + OFF_W3);
    float*  wT4 = (float*)(ws + OFF_W4);

    transpose_w_kernel<<<144, 256, 0, stream>>>(w_conv1, wT1);
    transpose_w_kernel<<<144, 256, 0, stream>>>(w_conv3, wT3);
    transpose_w_kernel<<<144, 256, 0, stream>>>(w_conv4, wT4);

    conv0_pool_kernel<<<16384, 256, 0, stream>>>(inputs, w_conv0, b_conv0, t0);
    conv64_kernel<0><<<1024, 256, 0, stream>>>(t0, wT1, b_conv1, t1, 32);
    pool_kernel<<<4096, 256, 0, stream>>>(t1, t2, 16);
    enc_kernel<<<64, 256, 0, stream>>>(t2, w_enc, b_enc, xE);

    lstm_kernel<<<64, 256, 0, stream>>>(xE, w_lstm_x, b_lstm, h);
    rowsum_kernel<<<3, 256, 0, stream>>>(w_out_, rs);
    gamma_kernel<<<64, 256, 0, stream>>>(h, w_param, b_param, rv);
    ntmout_kernel<<<64, 256, 0, stream>>>(h, w_out_, b_out_, rv, rs, ntm);

    conv1to64_kernel<<<4096, 256, 0, stream>>>(ntm, w_conv2, b_conv2, t4, 16);
    conv64_kernel<1><<<1024, 256, 0, stream>>>(t4, wT3, b_conv3, t5, 32);
    conv64_kernel<1><<<4096, 256, 0, stream>>>(t5, wT4, b_conv4, (float*)d_out, 64);
}

// Round 3
// 570.466 us; speedup vs baseline: 1.6984x; 1.6984x over previous
//
#include <hip/hip_runtime.h>

// ============================================================================
// Encoder (conv/pool) -> degenerate NTM step (zero-state collapse) -> Decoder.
// Round 3: conv path fp64 -> fp32 (measured ref-noise floor 3.8e-6 vs 2.41e-5
// threshold leaves ~2e-5 budget; fp32 reorder adds <1e-6). conv64 restructured:
// no sW LDS stage (weights via L1-resident global float4 reads, padded
// stride-12), LDS 55296->30720 B, occupancy 2->5 blocks/CU, single barrier.
// Tiny NTM kernels stay fp64 (cost < 10 us total).
// ============================================================================

// ---- workspace layout (bytes) ----
static const size_t OFF0   = 0;            // t0 conv0+pool (64,64,32,32) f32 16MB ; reused as t5 later
static const size_t OFF1   = 16777216;     // t1 conv1 out  (64,64,32,32) f32 16MB
static const size_t OFF2   = 33554432;     // t2 pool1 out  (64,64,16,16) f32  4MB
static const size_t OFF4   = 37748736;     // t4 conv2 out  (64,64,16,16) f32  4MB
static const size_t OFF_W1 = 41943040;     // wT12 conv1 (ci,co,12) f32 192KB
static const size_t OFF_W3 = 42139648;     // wT12 conv3
static const size_t OFF_W4 = 42336256;     // wT12 conv4
static const size_t OFF3   = 42532864;     // xE  (64,256) f32
static const size_t OFF_H  = 42598400;     // h   (64,256) f32
static const size_t OFF_RV = 42663936;     // rv  (64,3)   f64
static const size_t OFF_RS = 42665472;     // rs  (3,256)  f64
static const size_t OFF_N  = 42671616;     // ntm (64,256) f32   end ~42.7MB

// ---- transpose (co,ci,9) -> (ci,co,12-padded) for aligned float4 loads ----
__global__ void transpose_w_kernel(const float* __restrict__ w, float* __restrict__ wT) {
    int s = blockIdx.x * 256 + threadIdx.x;
    if (s >= 64 * 64 * 9) return;
    int co = s / 576; int rem = s % 576; int ci = rem / 9; int t = rem % 9;
    wT[(ci * 64 + co) * 12 + t] = w[s];
}

// ---- fused conv0 (1->64, 3x3 SAME, relu) + avgpool2 : (64,1,64,64) -> (64,64,32,32) ----
__global__ __launch_bounds__(256) void conv0_pool_kernel(
    const float* __restrict__ in, const float* __restrict__ w,
    const float* __restrict__ bias, float* __restrict__ out)
{
    int idx = blockIdx.x * 256 + threadIdx.x;           // 4,194,304 total
    int x = idx & 31, y = (idx >> 5) & 31, co = (idx >> 10) & 63, b = idx >> 16;
    float w9[9];
#pragma unroll
    for (int t = 0; t < 9; ++t) w9[t] = w[co * 9 + t];
    float bv = bias[co];
    const float* ip = in + (size_t)b * 4096;
    float p[4][4];
#pragma unroll
    for (int r = 0; r < 4; ++r) {
        int gy = 2 * y - 1 + r;
#pragma unroll
        for (int c = 0; c < 4; ++c) {
            int gx = 2 * x - 1 + c;
            float v = 0.f;
            if ((unsigned)gy < 64u && (unsigned)gx < 64u) v = ip[gy * 64 + gx];
            p[r][c] = v;
        }
    }
    float s4 = 0.f;
#pragma unroll
    for (int dy = 0; dy < 2; ++dy)
#pragma unroll
        for (int dx = 0; dx < 2; ++dx) {
            float a = bv;
#pragma unroll
            for (int ky = 0; ky < 3; ++ky)
#pragma unroll
                for (int kx = 0; kx < 3; ++kx)
                    a = fmaf(w9[ky * 3 + kx], p[dy + ky][dx + kx], a);
            s4 += fmaxf(a, 0.f);
        }
    out[idx] = s4 * 0.25f;
}

// ---- generic 64->64 3x3 SAME conv + relu, optional fused 2x upsample of src ----
// src (B,64,H>>UP,H>>UP) logical-upsampled to (H,H); out (B,64,H,H)
template <int UP>
__global__ __launch_bounds__(256, 5) void conv64_kernel(
    const float* __restrict__ src, const float* __restrict__ wT,
    const float* __restrict__ bias, float* __restrict__ out, int H)
{
    const int srcH = H >> UP;
    const int tpr = H >> 3;                 // tiles per row (8x8 tiles)
    int blk = blockIdx.x;
    int b = blk / (tpr * tpr);
    int tt = blk % (tpr * tpr);
    int y0 = (tt / tpr) * 8, x0 = (tt % tpr) * 8;
    const int tid = threadIdx.x;
    const int co = tid & 63;
    const int grp = tid >> 6;               // wave id; each wave owns 2 output rows

    __shared__ float sIn[7680];             // [64ci][10r][12c-padded]  30720B

    // stage input tile with halo (zero-padded SAME), fused upsample via >>UP
    for (int k = tid; k < 6400; k += 256) {
        int ci = k / 100; int r = (k / 10) % 10; int c = k % 10;
        int gy = y0 - 1 + r, gx = x0 - 1 + c;
        float v = 0.f;
        if ((unsigned)gy < (unsigned)H && (unsigned)gx < (unsigned)H)
            v = src[((size_t)(b * 64 + ci) * srcH + (gy >> UP)) * srcH + (gx >> UP)];
        sIn[(ci * 10 + r) * 12 + c] = v;
    }
    __syncthreads();

    float acc[16];
#pragma unroll
    for (int i = 0; i < 16; ++i) acc[i] = 0.f;
    const int rbase = grp * 2;

    const float4* wp = (const float4*)(wT + (size_t)co * 12);   // 48B-aligned
    const float4* rp = (const float4*)&sIn[rbase * 12];

    for (int ci = 0; ci < 64; ++ci) {
        // 12 wave-uniform (broadcast) LDS float4 reads: rows rbase..rbase+3
        float dr[4][12];
#pragma unroll
        for (int r = 0; r < 4; ++r) {
            float4 a = rp[r * 3 + 0]; float4 b4 = rp[r * 3 + 1]; float4 c4 = rp[r * 3 + 2];
            dr[r][0] = a.x;  dr[r][1] = a.y;  dr[r][2] = a.z;  dr[r][3] = a.w;
            dr[r][4] = b4.x; dr[r][5] = b4.y; dr[r][6] = b4.z; dr[r][7] = b4.w;
            dr[r][8] = c4.x; dr[r][9] = c4.y; dr[r][10] = c4.z; dr[r][11] = c4.w;
        }
        // 3 L1-resident global float4 reads: this co's 9 weights (12-padded)
        float4 w0 = wp[0], w1 = wp[1], w2 = wp[2];
        float w9[9] = { w0.x, w0.y, w0.z, w0.w, w1.x, w1.y, w1.z, w1.w, w2.x };
#pragma unroll
        for (int ky = 0; ky < 3; ++ky) {
#pragma unroll
            for (int kx = 0; kx < 3; ++kx) {
                float wv = w9[ky * 3 + kx];
#pragma unroll
                for (int px = 0; px < 8; ++px) {
                    acc[px]     = fmaf(wv, dr[ky][px + kx],     acc[px]);
                    acc[8 + px] = fmaf(wv, dr[ky + 1][px + kx], acc[8 + px]);
                }
            }
        }
        wp += 192;                          // next ci: +64co*12 floats
        rp += 30;                           // next ci: +10r*12c floats
    }

    float bv = bias[co];
#pragma unroll
    for (int pyl = 0; pyl < 2; ++pyl)
#pragma unroll
        for (int px = 0; px < 8; ++px) {
            float v = fmaxf(acc[pyl * 8 + px] + bv, 0.f);
            int y = y0 + rbase + pyl, x = x0 + px;
            out[((size_t)(b * 64 + co) * H + y) * H + x] = v;
        }
}

// ---- avgpool2: (64,64,2Ho,2Ho) -> (64,64,Ho,Ho) ----
__global__ void pool_kernel(const float* __restrict__ in, float* __restrict__ out, int Ho)
{
    int idx = blockIdx.x * 256 + threadIdx.x;
    int n = 64 * 64 * Ho * Ho;
    if (idx >= n) return;
    int x = idx % Ho; int y = (idx / Ho) % Ho; int p = idx / (Ho * Ho);
    int Hi = 2 * Ho;
    const float* ip = in + (size_t)p * Hi * Hi;
    float s = ip[(2 * y) * Hi + 2 * x] + ip[(2 * y) * Hi + 2 * x + 1]
            + ip[(2 * y + 1) * Hi + 2 * x] + ip[(2 * y + 1) * Hi + 2 * x + 1];
    out[idx] = s * 0.25f;
}

// ---- enc conv: 64->1, 16x16, relu -> x (64,256) ---- (fp64, tiny)
__global__ __launch_bounds__(256) void enc_kernel(
    const float* __restrict__ in, const float* __restrict__ w,
    const float* __restrict__ bias, float* __restrict__ xout)
{
    int b = blockIdx.x; int tid = threadIdx.x;
    int y = tid >> 4, x = tid & 15;
    __shared__ float sE[8192];
    double acc = 0.0;
    for (int ch = 0; ch < 2; ++ch) {
        __syncthreads();
        for (int k = tid; k < 8192; k += 256) sE[k] = in[(size_t)b * 16384 + ch * 8192 + k];
        __syncthreads();
        for (int cip = 0; cip < 32; ++cip) {
            int ci = ch * 32 + cip;
#pragma unroll
            for (int ky = 0; ky < 3; ++ky) {
                int gy = y + ky - 1;
                if ((unsigned)gy >= 16u) continue;
#pragma unroll
                for (int kx = 0; kx < 3; ++kx) {
                    int gx = x + kx - 1;
                    if ((unsigned)gx >= 16u) continue;
                    acc = fma((double)w[ci * 9 + ky * 3 + kx],
                              (double)sE[cip * 256 + gy * 16 + gx], acc);
                }
            }
        }
    }
    float v = (float)(acc + (double)bias[0]);
    xout[b * 256 + tid] = fmaxf(v, 0.f);
}

// ---- LSTM (zero state): h = sig(zo)*tanh(sig(zi)*tanh(zg)), z = x @ Wx[:256] + b ----
__global__ __launch_bounds__(256) void lstm_kernel(
    const float* __restrict__ x, const float* __restrict__ wx,
    const float* __restrict__ bl, float* __restrict__ h)
{
    int b = blockIdx.x, j = threadIdx.x;
    __shared__ float sx[256];
    sx[j] = x[b * 256 + j];
    __syncthreads();
    double zi = 0, zg = 0, zo = 0;
    for (int d = 0; d < 256; ++d) {
        double xv = (double)sx[d];
        const float* row = wx + (size_t)d * 1024;
        zi = fma(xv, (double)row[j], zi);
        zg = fma(xv, (double)row[512 + j], zg);
        zo = fma(xv, (double)row[768 + j], zo);
    }
    float zif = (float)(zi + (double)bl[j]);
    float zgf = (float)(zg + (double)bl[512 + j]);
    float zof = (float)(zo + (double)bl[768 + j]);
    double c = (1.0 / (1.0 + exp(-(double)zif))) * tanh((double)zgf);
    float cf = (float)c;
    double hh = (1.0 / (1.0 + exp(-(double)zof))) * tanh((double)cf);
    h[b * 256 + j] = (float)hh;
}

// ---- rowsums of w_out reads-block: rs[r][m] = sum_d w_out[256+r*256+d, m] ----
__global__ void rowsum_kernel(const float* __restrict__ w_out, double* __restrict__ rs)
{
    int r = blockIdx.x, m = threadIdx.x;
    double s = 0;
    for (int d = 0; d < 256; ++d) s += (double)w_out[(size_t)(256 + r * 256 + d) * 256 + m];
    rs[r * 256 + m] = s;
}

// ---- read-head scalar: rv[b,r] = 64e-6 * q/(64q+1e-8), q=(1/64+1e-16)^gamma ----
__global__ __launch_bounds__(256) void gamma_kernel(
    const float* __restrict__ h, const float* __restrict__ w_param,
    const float* __restrict__ b_param, double* __restrict__ rv)
{
    int b = blockIdx.x, t = threadIdx.x;
    __shared__ double sp[3][256];
    float hv = h[b * 256 + t];
#pragma unroll
    for (int r = 0; r < 3; ++r)
        sp[r][t] = (double)hv * (double)w_param[(size_t)t * 3108 + r * 262 + 261];
    __syncthreads();
    if (t < 3) {
        double s = 0;
        for (int d = 0; d < 256; ++d) s += sp[t][d];
        float pf = (float)(s + (double)b_param[t * 262 + 261]);
        pf = fminf(fmaxf(pf, -20.f), 20.f);                 // CLIP
        double gamma = log1p(exp((double)pf)) + 1.0;        // softplus + 1
        double q = pow(0.015625 + 1e-16, gamma);
        double wv = q / (64.0 * q + 1e-8);
        rv[b * 3 + t] = wv * 64.0 * 1e-6;
    }
}

// ---- ntm out: clip(h@w_out[:256] + b_out + sum_r rv_r*rs_r, +-20) ----
__global__ __launch_bounds__(256) void ntmout_kernel(
    const float* __restrict__ h, const float* __restrict__ w_out,
    const float* __restrict__ b_out, const double* __restrict__ rv,
    const double* __restrict__ rs, float* __restrict__ out)
{
    int b = blockIdx.x, m = threadIdx.x;
    __shared__ float sh[256];
    __shared__ double srv[3];
    sh[m] = h[b * 256 + m];
    if (m < 3) srv[m] = rv[b * 3 + m];
    __syncthreads();
    double acc = 0;
    for (int d = 0; d < 256; ++d)
        acc = fma((double)sh[d], (double)w_out[(size_t)d * 256 + m], acc);
    acc += (double)b_out[m];
#pragma unroll
    for (int r = 0; r < 3; ++r) acc += srv[r] * rs[r * 256 + m];
    acc = fmin(fmax(acc, -20.0), 20.0);
    out[b * 256 + m] = (float)acc;
}

// ---- 1->64 3x3 SAME conv + relu (conv2, H=16) ----
__global__ void conv1to64_kernel(
    const float* __restrict__ in, const float* __restrict__ w,
    const float* __restrict__ bias, float* __restrict__ out, int H)
{
    int idx = blockIdx.x * 256 + threadIdx.x;
    int HH = H * H;
    int x = idx % H; int y = (idx / H) % H; int co = (idx / HH) & 63; int b = idx / (HH * 64);
    float acc = bias[co];
    const float* ip = in + (size_t)b * HH;
#pragma unroll
    for (int ky = 0; ky < 3; ++ky) {
        int gy = y + ky - 1;
        if ((unsigned)gy >= (unsigned)H) continue;
#pragma unroll
        for (int kx = 0; kx < 3; ++kx) {
            int gx = x + kx - 1;
            if ((unsigned)gx >= (unsigned)H) continue;
            acc = fmaf(w[co * 9 + ky * 3 + kx], ip[gy * H + gx], acc);
        }
    }
    out[idx] = fmaxf(acc, 0.f);
}

extern "C" void kernel_launch(void* const* d_in, const int* in_sizes, int n_in,
                              void* d_out, int out_size, void* d_ws, size_t ws_size,
                              hipStream_t stream)
{
    const float* inputs   = (const float*)d_in[0];
    const float* w_conv0  = (const float*)d_in[1];
    const float* b_conv0  = (const float*)d_in[2];
    const float* w_conv1  = (const float*)d_in[3];
    const float* b_conv1  = (const float*)d_in[4];
    const float* w_enc    = (const float*)d_in[5];
    const float* b_enc    = (const float*)d_in[6];
    const float* w_conv2  = (const float*)d_in[7];
    const float* b_conv2  = (const float*)d_in[8];
    const float* w_conv3  = (const float*)d_in[9];
    const float* b_conv3  = (const float*)d_in[10];
    const float* w_conv4  = (const float*)d_in[11];
    const float* b_conv4  = (const float*)d_in[12];
    const float* w_lstm_x = (const float*)d_in[13];
    // d_in[14] = w_lstm_h : dead (h0 == 0)
    const float* b_lstm   = (const float*)d_in[15];
    const float* w_param  = (const float*)d_in[16];
    const float* b_param  = (const float*)d_in[17];
    const float* w_out_   = (const float*)d_in[18];
    const float* b_out_   = (const float*)d_in[19];

    char* ws = (char*)d_ws;
    float*  t0  = (float*)(ws + OFF0);
    float*  t1  = (float*)(ws + OFF1);
    float*  t2  = (float*)(ws + OFF2);
    float*  t4  = (float*)(ws + OFF4);
    float*  t5  = (float*)(ws + OFF0);     // reuse t0 (dead after conv1)
    float*  wT1 = (float*)(ws + OFF_W1);
    float*  wT3 = (float*)(ws + OFF_W3);
    float*  wT4 = (float*)(ws + OFF_W4);
    float*  xE  = (float*)(ws + OFF3);
    float*  h   = (float*)(ws + OFF_H);
    double* rv  = (double*)(ws + OFF_RV);
    double* rs  = (double*)(ws + OFF_RS);
    float*  ntm = (float*)(ws + OFF_N);

    transpose_w_kernel<<<144, 256, 0, stream>>>(w_conv1, wT1);
    transpose_w_kernel<<<144, 256, 0, stream>>>(w_conv3, wT3);
    transpose_w_kernel<<<144, 256, 0, stream>>>(w_conv4, wT4);

    conv0_pool_kernel<<<16384, 256, 0, stream>>>(inputs, w_conv0, b_conv0, t0);
    conv64_kernel<0><<<1024, 256, 0, stream>>>(t0, wT1, b_conv1, t1, 32);
    pool_kernel<<<4096, 256, 0, stream>>>(t1, t2, 16);
    enc_kernel<<<64, 256, 0, stream>>>(t2, w_enc, b_enc, xE);

    lstm_kernel<<<64, 256, 0, stream>>>(xE, w_lstm_x, b_lstm, h);
    rowsum_kernel<<<3, 256, 0, stream>>>(w_out_, rs);
    gamma_kernel<<<64, 256, 0, stream>>>(h, w_param, b_param, rv);
    ntmout_kernel<<<64, 256, 0, stream>>>(h, w_out_, b_out_, rv, rs, ntm);

    conv1to64_kernel<<<4096, 256, 0, stream>>>(ntm, w_conv2, b_conv2, t4, 16);
    conv64_kernel<1><<<1024, 256, 0, stream>>>(t4, wT3, b_conv3, t5, 32);
    conv64_kernel<1><<<4096, 256, 0, stream>>>(t5, wT4, b_conv4, (float*)d_out, 64);
}

// Round 4
// 458.095 us; speedup vs baseline: 2.1150x; 1.2453x over previous
//
#include <hip/hip_runtime.h>
#include <hip/hip_bf16.h>

// ============================================================================
// Round 4: 64->64 convs (conv1/conv3/conv4, ~440us of 570) -> MFMA implicit
// GEMM with split-bf16 3-pass (x_hi*w_hi + x_hi*w_lo + x_lo*w_hi), error
// ~2^-17 relative (~2e-8 absolute at output scale) vs measured 2.41e-5
// threshold / 3.8e-6 bf16-ref floor. A (im2col) from LDS [18][18][72-pad]
// bf16 hi/lo; B (weights, [t][co][ci] hi/lo) from global/L1 -> LDS pipe
// reserved for A. 16x16x32 MFMA; M=pixel-col, N=co. Rest unchanged.
// ============================================================================

typedef __attribute__((ext_vector_type(8))) short short8;
typedef __attribute__((ext_vector_type(4))) float f32x4;

// ---- workspace layout (bytes) ----
static const size_t OFF0   = 0;            // t0 conv0+pool (64,64,32,32) f32 16MB ; reused as t5
static const size_t OFF1   = 16777216;     // t1 conv1 out  (64,64,32,32) f32 16MB
static const size_t OFF2   = 33554432;     // t2 pool1 out  (64,64,16,16) f32  4MB
static const size_t OFF4   = 37748736;     // t4 conv2 out  (64,64,16,16) f32  4MB
static const size_t OFF_W1 = 41943040;     // whi1+wlo1 (9,64,64) bf16 2x72KB
static const size_t OFF_W3 = 42139648;     // whi3+wlo3
static const size_t OFF_W4 = 42336256;     // whi4+wlo4
static const size_t OFF3   = 42532864;     // xE  (64,256) f32
static const size_t OFF_H  = 42598400;     // h   (64,256) f32
static const size_t OFF_RV = 42663936;     // rv  (64,3)   f64
static const size_t OFF_RS = 42665472;     // rs  (3,256)  f64
static const size_t OFF_N  = 42671616;     // ntm (64,256) f32   end ~42.7MB

// ---- weight prep: (co,ci,3,3) f32 -> whi/wlo [t][co][ci] bf16 (split) ----
__global__ void wprep_kernel(const float* __restrict__ w,
                             unsigned short* __restrict__ whi,
                             unsigned short* __restrict__ wlo)
{
    int s = blockIdx.x * 256 + threadIdx.x;
    if (s >= 36864) return;
    int co = s / 576; int rem = s % 576; int ci = rem / 9; int t = rem % 9;
    float v = w[s];
    __hip_bfloat16 h = __float2bfloat16(v);
    float hf = __bfloat162float(h);
    __hip_bfloat16 l = __float2bfloat16(v - hf);
    int d = (t * 64 + co) * 64 + ci;
    whi[d] = __builtin_bit_cast(unsigned short, h);
    wlo[d] = __builtin_bit_cast(unsigned short, l);
}

// ---- MFMA implicit-GEMM 64->64 3x3 SAME conv + relu, optional upsampled src ----
// Block: 16x16 out-pixel tile of one image, 512 thr (8 waves).
// Wave wv owns tile rows {2wv, 2wv+1}; M = 16 pixel-cols, N = 64 co (4 frags).
template <int UP>
__global__ __launch_bounds__(512, 1) void conv_mfma_kernel(
    const float* __restrict__ src, const unsigned short* __restrict__ whi,
    const unsigned short* __restrict__ wlo, const float* __restrict__ bias,
    float* __restrict__ out, int H)
{
    const int srcH = H >> UP;
    const int tpr = H >> 4;
    int b  = blockIdx.x / (tpr * tpr);
    int tt = blockIdx.x % (tpr * tpr);
    int y0 = (tt / tpr) * 16, x0 = (tt % tpr) * 16;
    const int tid = threadIdx.x;
    const int wv = tid >> 6, lane = tid & 63;
    const int lc = lane & 15, kg = lane >> 4;      // lc: M/N frag index, kg: k-group

    __shared__ unsigned short ahi[18 * 18 * 72];   // [r][c][ci pad72] 46656B
    __shared__ unsigned short alo[18 * 18 * 72];   // + 46656B = 93312B total

    // stage halo'd input tile, split to bf16 hi/lo (c innermost -> coalesced)
    for (int k = tid; k < 18 * 18 * 64; k += 512) {
        int ci = k / 324; int rc = k - ci * 324; int r = rc / 18, c = rc - r * 18;
        int gy = y0 - 1 + r, gx = x0 - 1 + c;
        float v = 0.f;
        if ((unsigned)gy < (unsigned)H && (unsigned)gx < (unsigned)H)
            v = src[((size_t)(b * 64 + ci) * srcH + (gy >> UP)) * srcH + (gx >> UP)];
        __hip_bfloat16 h = __float2bfloat16(v);
        float hf = __bfloat162float(h);
        __hip_bfloat16 l = __float2bfloat16(v - hf);
        int a = (r * 18 + c) * 72 + ci;
        ahi[a] = __builtin_bit_cast(unsigned short, h);
        alo[a] = __builtin_bit_cast(unsigned short, l);
    }
    __syncthreads();

    f32x4 zero = {0.f, 0.f, 0.f, 0.f};
    f32x4 acc[2][4];
#pragma unroll
    for (int m = 0; m < 2; ++m)
#pragma unroll
        for (int n = 0; n < 4; ++n) acc[m][n] = zero;

    for (int t = 0; t < 9; ++t) {
        int ky = t / 3, kx = t - ky * 3;
#pragma unroll
        for (int ch = 0; ch < 2; ++ch) {
            short8 ah[2], al[2];
#pragma unroll
            for (int m = 0; m < 2; ++m) {
                int base = ((2 * wv + m + ky) * 18 + lc + kx) * 72 + ch * 32 + kg * 8;
                ah[m] = *(const short8*)&ahi[base];
                al[m] = *(const short8*)&alo[base];
            }
#pragma unroll
            for (int n = 0; n < 4; ++n) {
                int wb = (t * 64 + n * 16 + lc) * 64 + ch * 32 + kg * 8;
                short8 bh = *(const short8*)&whi[wb];
                short8 bl = *(const short8*)&wlo[wb];
#pragma unroll
                for (int m = 0; m < 2; ++m) {
                    acc[m][n] = __builtin_amdgcn_mfma_f32_16x16x32_bf16(ah[m], bh, acc[m][n], 0, 0, 0);
                    acc[m][n] = __builtin_amdgcn_mfma_f32_16x16x32_bf16(ah[m], bl, acc[m][n], 0, 0, 0);
                    acc[m][n] = __builtin_amdgcn_mfma_f32_16x16x32_bf16(al[m], bh, acc[m][n], 0, 0, 0);
                }
            }
        }
    }

    // epilogue: D layout col(N)=lane&15, row(M)=kg*4+reg -> float4 along x
#pragma unroll
    for (int n = 0; n < 4; ++n) {
        int co = n * 16 + lc;
        float bv = bias[co];
#pragma unroll
        for (int m = 0; m < 2; ++m) {
            int row = y0 + 2 * wv + m;
            int cb = x0 + kg * 4;
            f32x4 v = acc[m][n];
            f32x4 res;
            res.x = fmaxf(v.x + bv, 0.f);
            res.y = fmaxf(v.y + bv, 0.f);
            res.z = fmaxf(v.z + bv, 0.f);
            res.w = fmaxf(v.w + bv, 0.f);
            *(f32x4*)&out[((size_t)(b * 64 + co) * H + row) * H + cb] = res;
        }
    }
}

// ---- fused conv0 (1->64, 3x3 SAME, relu) + avgpool2 : (64,1,64,64) -> (64,64,32,32) ----
__global__ __launch_bounds__(256) void conv0_pool_kernel(
    const float* __restrict__ in, const float* __restrict__ w,
    const float* __restrict__ bias, float* __restrict__ out)
{
    int idx = blockIdx.x * 256 + threadIdx.x;
    int x = idx & 31, y = (idx >> 5) & 31, co = (idx >> 10) & 63, b = idx >> 16;
    float w9[9];
#pragma unroll
    for (int t = 0; t < 9; ++t) w9[t] = w[co * 9 + t];
    float bv = bias[co];
    const float* ip = in + (size_t)b * 4096;
    float p[4][4];
#pragma unroll
    for (int r = 0; r < 4; ++r) {
        int gy = 2 * y - 1 + r;
#pragma unroll
        for (int c = 0; c < 4; ++c) {
            int gx = 2 * x - 1 + c;
            float v = 0.f;
            if ((unsigned)gy < 64u && (unsigned)gx < 64u) v = ip[gy * 64 + gx];
            p[r][c] = v;
        }
    }
    float s4 = 0.f;
#pragma unroll
    for (int dy = 0; dy < 2; ++dy)
#pragma unroll
        for (int dx = 0; dx < 2; ++dx) {
            float a = bv;
#pragma unroll
            for (int ky = 0; ky < 3; ++ky)
#pragma unroll
                for (int kx = 0; kx < 3; ++kx)
                    a = fmaf(w9[ky * 3 + kx], p[dy + ky][dx + kx], a);
            s4 += fmaxf(a, 0.f);
        }
    out[idx] = s4 * 0.25f;
}

// ---- avgpool2: (64,64,2Ho,2Ho) -> (64,64,Ho,Ho) ----
__global__ void pool_kernel(const float* __restrict__ in, float* __restrict__ out, int Ho)
{
    int idx = blockIdx.x * 256 + threadIdx.x;
    int n = 64 * 64 * Ho * Ho;
    if (idx >= n) return;
    int x = idx % Ho; int y = (idx / Ho) % Ho; int p = idx / (Ho * Ho);
    int Hi = 2 * Ho;
    const float* ip = in + (size_t)p * Hi * Hi;
    float s = ip[(2 * y) * Hi + 2 * x] + ip[(2 * y) * Hi + 2 * x + 1]
            + ip[(2 * y + 1) * Hi + 2 * x] + ip[(2 * y + 1) * Hi + 2 * x + 1];
    out[idx] = s * 0.25f;
}

// ---- enc conv: 64->1, 16x16, relu -> x (64,256) ----
__global__ __launch_bounds__(256) void enc_kernel(
    const float* __restrict__ in, const float* __restrict__ w,
    const float* __restrict__ bias, float* __restrict__ xout)
{
    int b = blockIdx.x; int tid = threadIdx.x;
    int y = tid >> 4, x = tid & 15;
    __shared__ float sE[8192];
    double acc = 0.0;
    for (int ch = 0; ch < 2; ++ch) {
        __syncthreads();
        for (int k = tid; k < 8192; k += 256) sE[k] = in[(size_t)b * 16384 + ch * 8192 + k];
        __syncthreads();
        for (int cip = 0; cip < 32; ++cip) {
            int ci = ch * 32 + cip;
#pragma unroll
            for (int ky = 0; ky < 3; ++ky) {
                int gy = y + ky - 1;
                if ((unsigned)gy >= 16u) continue;
#pragma unroll
                for (int kx = 0; kx < 3; ++kx) {
                    int gx = x + kx - 1;
                    if ((unsigned)gx >= 16u) continue;
                    acc = fma((double)w[ci * 9 + ky * 3 + kx],
                              (double)sE[cip * 256 + gy * 16 + gx], acc);
                }
            }
        }
    }
    float v = (float)(acc + (double)bias[0]);
    xout[b * 256 + tid] = fmaxf(v, 0.f);
}

// ---- LSTM (zero state): h = sig(zo)*tanh(sig(zi)*tanh(zg)) ----
__global__ __launch_bounds__(256) void lstm_kernel(
    const float* __restrict__ x, const float* __restrict__ wx,
    const float* __restrict__ bl, float* __restrict__ h)
{
    int b = blockIdx.x, j = threadIdx.x;
    __shared__ float sx[256];
    sx[j] = x[b * 256 + j];
    __syncthreads();
    double zi = 0, zg = 0, zo = 0;
    for (int d = 0; d < 256; ++d) {
        double xv = (double)sx[d];
        const float* row = wx + (size_t)d * 1024;
        zi = fma(xv, (double)row[j], zi);
        zg = fma(xv, (double)row[512 + j], zg);
        zo = fma(xv, (double)row[768 + j], zo);
    }
    float zif = (float)(zi + (double)bl[j]);
    float zgf = (float)(zg + (double)bl[512 + j]);
    float zof = (float)(zo + (double)bl[768 + j]);
    double c = (1.0 / (1.0 + exp(-(double)zif))) * tanh((double)zgf);
    float cf = (float)c;
    double hh = (1.0 / (1.0 + exp(-(double)zof))) * tanh((double)cf);
    h[b * 256 + j] = (float)hh;
}

// ---- rowsums of w_out reads-block ----
__global__ void rowsum_kernel(const float* __restrict__ w_out, double* __restrict__ rs)
{
    int r = blockIdx.x, m = threadIdx.x;
    double s = 0;
    for (int d = 0; d < 256; ++d) s += (double)w_out[(size_t)(256 + r * 256 + d) * 256 + m];
    rs[r * 256 + m] = s;
}

// ---- read-head scalar rv[b,r] ----
__global__ __launch_bounds__(256) void gamma_kernel(
    const float* __restrict__ h, const float* __restrict__ w_param,
    const float* __restrict__ b_param, double* __restrict__ rv)
{
    int b = blockIdx.x, t = threadIdx.x;
    __shared__ double sp[3][256];
    float hv = h[b * 256 + t];
#pragma unroll
    for (int r = 0; r < 3; ++r)
        sp[r][t] = (double)hv * (double)w_param[(size_t)t * 3108 + r * 262 + 261];
    __syncthreads();
    if (t < 3) {
        double s = 0;
        for (int d = 0; d < 256; ++d) s += sp[t][d];
        float pf = (float)(s + (double)b_param[t * 262 + 261]);
        pf = fminf(fmaxf(pf, -20.f), 20.f);
        double gamma = log1p(exp((double)pf)) + 1.0;
        double q = pow(0.015625 + 1e-16, gamma);
        double wv = q / (64.0 * q + 1e-8);
        rv[b * 3 + t] = wv * 64.0 * 1e-6;
    }
}

// ---- ntm out: clip(h@w_out[:256] + b_out + sum_r rv_r*rs_r, +-20) ----
__global__ __launch_bounds__(256) void ntmout_kernel(
    const float* __restrict__ h, const float* __restrict__ w_out,
    const float* __restrict__ b_out, const double* __restrict__ rv,
    const double* __restrict__ rs, float* __restrict__ out)
{
    int b = blockIdx.x, m = threadIdx.x;
    __shared__ float sh[256];
    __shared__ double srv[3];
    sh[m] = h[b * 256 + m];
    if (m < 3) srv[m] = rv[b * 3 + m];
    __syncthreads();
    double acc = 0;
    for (int d = 0; d < 256; ++d)
        acc = fma((double)sh[d], (double)w_out[(size_t)d * 256 + m], acc);
    acc += (double)b_out[m];
#pragma unroll
    for (int r = 0; r < 3; ++r) acc += srv[r] * rs[r * 256 + m];
    acc = fmin(fmax(acc, -20.0), 20.0);
    out[b * 256 + m] = (float)acc;
}

// ---- 1->64 3x3 SAME conv + relu (conv2, H=16) ----
__global__ void conv1to64_kernel(
    const float* __restrict__ in, const float* __restrict__ w,
    const float* __restrict__ bias, float* __restrict__ out, int H)
{
    int idx = blockIdx.x * 256 + threadIdx.x;
    int HH = H * H;
    int x = idx % H; int y = (idx / H) % H; int co = (idx / HH) & 63; int b = idx / (HH * 64);
    float acc = bias[co];
    const float* ip = in + (size_t)b * HH;
#pragma unroll
    for (int ky = 0; ky < 3; ++ky) {
        int gy = y + ky - 1;
        if ((unsigned)gy >= (unsigned)H) continue;
#pragma unroll
        for (int kx = 0; kx < 3; ++kx) {
            int gx = x + kx - 1;
            if ((unsigned)gx >= (unsigned)H) continue;
            acc = fmaf(w[co * 9 + ky * 3 + kx], ip[gy * H + gx], acc);
        }
    }
    out[idx] = fmaxf(acc, 0.f);
}

extern "C" void kernel_launch(void* const* d_in, const int* in_sizes, int n_in,
                              void* d_out, int out_size, void* d_ws, size_t ws_size,
                              hipStream_t stream)
{
    const float* inputs   = (const float*)d_in[0];
    const float* w_conv0  = (const float*)d_in[1];
    const float* b_conv0  = (const float*)d_in[2];
    const float* w_conv1  = (const float*)d_in[3];
    const float* b_conv1  = (const float*)d_in[4];
    const float* w_enc    = (const float*)d_in[5];
    const float* b_enc    = (const float*)d_in[6];
    const float* w_conv2  = (const float*)d_in[7];
    const float* b_conv2  = (const float*)d_in[8];
    const float* w_conv3  = (const float*)d_in[9];
    const float* b_conv3  = (const float*)d_in[10];
    const float* w_conv4  = (const float*)d_in[11];
    const float* b_conv4  = (const float*)d_in[12];
    const float* w_lstm_x = (const float*)d_in[13];
    // d_in[14] = w_lstm_h : dead (h0 == 0)
    const float* b_lstm   = (const float*)d_in[15];
    const float* w_param  = (const float*)d_in[16];
    const float* b_param  = (const float*)d_in[17];
    const float* w_out_   = (const float*)d_in[18];
    const float* b_out_   = (const float*)d_in[19];

    char* ws = (char*)d_ws;
    float*  t0  = (float*)(ws + OFF0);
    float*  t1  = (float*)(ws + OFF1);
    float*  t2  = (float*)(ws + OFF2);
    float*  t4  = (float*)(ws + OFF4);
    float*  t5  = (float*)(ws + OFF0);     // reuse t0 (dead after conv1)
    unsigned short* whi1 = (unsigned short*)(ws + OFF_W1);
    unsigned short* wlo1 = whi1 + 36864;
    unsigned short* whi3 = (unsigned short*)(ws + OFF_W3);
    unsigned short* wlo3 = whi3 + 36864;
    unsigned short* whi4 = (unsigned short*)(ws + OFF_W4);
    unsigned short* wlo4 = whi4 + 36864;
    float*  xE  = (float*)(ws + OFF3);
    float*  h   = (float*)(ws + OFF_H);
    double* rv  = (double*)(ws + OFF_RV);
    double* rs  = (double*)(ws + OFF_RS);
    float*  ntm = (float*)(ws + OFF_N);

    wprep_kernel<<<144, 256, 0, stream>>>(w_conv1, whi1, wlo1);
    wprep_kernel<<<144, 256, 0, stream>>>(w_conv3, whi3, wlo3);
    wprep_kernel<<<144, 256, 0, stream>>>(w_conv4, whi4, wlo4);

    conv0_pool_kernel<<<16384, 256, 0, stream>>>(inputs, w_conv0, b_conv0, t0);
    conv_mfma_kernel<0><<<256, 512, 0, stream>>>(t0, whi1, wlo1, b_conv1, t1, 32);
    pool_kernel<<<4096, 256, 0, stream>>>(t1, t2, 16);
    enc_kernel<<<64, 256, 0, stream>>>(t2, w_enc, b_enc, xE);

    lstm_kernel<<<64, 256, 0, stream>>>(xE, w_lstm_x, b_lstm, h);
    rowsum_kernel<<<3, 256, 0, stream>>>(w_out_, rs);
    gamma_kernel<<<64, 256, 0, stream>>>(h, w_param, b_param, rv);
    ntmout_kernel<<<64, 256, 0, stream>>>(h, w_out_, b_out_, rv, rs, ntm);

    conv1to64_kernel<<<4096, 256, 0, stream>>>(ntm, w_conv2, b_conv2, t4, 16);
    conv_mfma_kernel<1><<<256, 512, 0, stream>>>(t4, whi3, wlo3, b_conv3, t5, 32);
    conv_mfma_kernel<1><<<1024, 512, 0, stream>>>(t5, whi4, wlo4, b_conv4, (float*)d_out, 64);
}

// Round 6
// 430.288 us; speedup vs baseline: 2.2516x; 1.0646x over previous
//
#include <hip/hip_runtime.h>
#include <hip/hip_bf16.h>

// ============================================================================
// Round 6: fix round-5 workspace aliasing bug. A4 (conv4 input NHWC) had been
// aliased onto t1 but is 18.9MB > t1's 16.8MB -> a4l overlapped t2's first
// 2.16MB, and halo_zero(a4) (after pool, before enc) scattered zeros into the
// pool output -> full-scale error. Fix: A4 reuses A1 (identical shape, dead
// after conv1); drop the second halo_zero (a1's ring stays zero all launch:
// only interior cells are ever written by conv0_pool / conv3 epilogue).
// Everything else identical to round 5 (LDS-free NHWC MFMA convs, split-bf16).
// ============================================================================

typedef __attribute__((ext_vector_type(8))) short short8;
typedef __attribute__((ext_vector_type(4))) float f32x4;

// ---- workspace layout (bytes) ----
// A1: conv1 input NHWC hi/lo, 32x32 interior (34x34 halo'd); reused as A4.
static const size_t OFF_A1H = 0;                       // 9,469,952
static const size_t OFF_A1L = 9469952;                 // -> end 18,939,904
static const size_t OFF_T1  = 18939904;                // t1 conv1 out NCHW f32 16MB -> 35,717,120
static const size_t OFF_T2  = 35717120;                // t2 pool1 out NCHW f32 4MB -> 39,911,424
static const size_t OFF_A3H = 39911424;                // conv3 input NHWC 16x16 (18x18) 2,654,208
static const size_t OFF_A3L = 42565632;                // -> end 45,219,840
static const size_t OFF_W1  = 45219840;                // whi+wlo (9,64,64) bf16, 147,456/layer
static const size_t OFF_W3  = 45367296;
static const size_t OFF_W4  = 45514752;
static const size_t OFF_XE  = 45662208;                // xE (64,256) f32
static const size_t OFF_H   = 45727744;                // h  (64,256) f32
static const size_t OFF_RV  = 45793280;                // rv (64,3) f64
static const size_t OFF_RS  = 45794816;                // rs (3,256) f64
static const size_t OFF_N   = 45800960;                // ntm (64,256) f32 -> ~45.9MB

__device__ inline void bf16split(float v, unsigned short& h, unsigned short& l) {
    __hip_bfloat16 hb = __float2bfloat16(v);
    float hf = __bfloat162float(hb);
    __hip_bfloat16 lb = __float2bfloat16(v - hf);
    h = __builtin_bit_cast(unsigned short, hb);
    l = __builtin_bit_cast(unsigned short, lb);
}

// ---- weight prep: (co,ci,3,3) f32 -> whi/wlo [t][co][ci] bf16 (split) ----
__global__ void wprep_kernel(const float* __restrict__ w,
                             unsigned short* __restrict__ whi,
                             unsigned short* __restrict__ wlo)
{
    int s = blockIdx.x * 256 + threadIdx.x;
    if (s >= 36864) return;
    int co = s / 576; int rem = s % 576; int ci = rem / 9; int t = rem % 9;
    unsigned short h, l;
    bf16split(w[s], h, l);
    int d = (t * 64 + co) * 64 + ci;
    whi[d] = h; wlo[d] = l;
}

// ---- zero the 1-px halo ring of an NHWC (B,S+2,S+2,64) hi/lo pair ----
__global__ void halo_zero_kernel(unsigned short* __restrict__ hi,
                                 unsigned short* __restrict__ lo, int S)
{
    int P = S + 2, ring = 4 * S + 4;
    int idx = blockIdx.x * 256 + threadIdx.x;
    if (idx >= 64 * ring * 64) return;
    int co = idx & 63;
    int cell = (idx >> 6) % ring;
    int b = (idx >> 6) / ring;
    int y, x;
    if (cell < P)            { y = 0;     x = cell; }
    else if (cell < 2 * P)   { y = P - 1; x = cell - P; }
    else { int c2 = cell - 2 * P; y = 1 + (c2 >> 1); x = (c2 & 1) ? P - 1 : 0; }
    size_t a = ((size_t)(b * P + y) * P + x) * 64 + co;
    hi[a] = 0; lo[a] = 0;
}

// ---- fused conv0 (1->64, 3x3 SAME, relu) + avgpool2 -> A1 NHWC hi/lo interior ----
__global__ __launch_bounds__(256) void conv0_pool_kernel(
    const float* __restrict__ in, const float* __restrict__ w,
    const float* __restrict__ bias,
    unsigned short* __restrict__ ohi, unsigned short* __restrict__ olo)
{
    int idx = blockIdx.x * 256 + threadIdx.x;      // 64*32*32*64 = 4,194,304
    int co = idx & 63, x = (idx >> 6) & 31, y = (idx >> 11) & 31, b = idx >> 16;
    float w9[9];
#pragma unroll
    for (int t = 0; t < 9; ++t) w9[t] = w[co * 9 + t];
    float bv = bias[co];
    const float* ip = in + (size_t)b * 4096;
    float p[4][4];
#pragma unroll
    for (int r = 0; r < 4; ++r) {
        int gy = 2 * y - 1 + r;
#pragma unroll
        for (int c = 0; c < 4; ++c) {
            int gx = 2 * x - 1 + c;
            float v = 0.f;
            if ((unsigned)gy < 64u && (unsigned)gx < 64u) v = ip[gy * 64 + gx];
            p[r][c] = v;
        }
    }
    float s4 = 0.f;
#pragma unroll
    for (int dy = 0; dy < 2; ++dy)
#pragma unroll
        for (int dx = 0; dx < 2; ++dx) {
            float a = bv;
#pragma unroll
            for (int ky = 0; ky < 3; ++ky)
#pragma unroll
                for (int kx = 0; kx < 3; ++kx)
                    a = fmaf(w9[ky * 3 + kx], p[dy + ky][dx + kx], a);
            s4 += fmaxf(a, 0.f);
        }
    unsigned short h, l;
    bf16split(s4 * 0.25f, h, l);
    size_t a = ((size_t)(b * 34 + y + 1) * 34 + x + 1) * 64 + co;   // coalesced (co inner)
    ohi[a] = h; olo[a] = l;
}

// ---- LDS-free MFMA implicit-GEMM 64->64 3x3 SAME conv + relu ----
// Input: NHWC bf16 hi/lo, (B, srcH+2, srcH+2, 64) with zero halo; logical 2x
// upsample via UP (arith >>: gy=-1 -> -1, gy=H -> srcH, both halo cells).
// Block: 16x16 out-pixel tile, 512 thr / 8 waves; wave owns rows {2wv,2wv+1}.
// M=16 pixel-cols (lc), N=64 co (4 frags), K=ci(64, 2 ch chunks) x 9 taps.
template <int UP, bool NHWC_OUT>
__global__ __launch_bounds__(512) void conv_mfma_kernel(
    const unsigned short* __restrict__ ahi, const unsigned short* __restrict__ alo,
    const unsigned short* __restrict__ whi, const unsigned short* __restrict__ wlo,
    const float* __restrict__ bias,
    float* __restrict__ outf, unsigned short* __restrict__ ohi,
    unsigned short* __restrict__ olo, int H)
{
    const int srcH = H >> UP;
    const int pitch = srcH + 2;
    const int tpr = H >> 4;
    int b  = blockIdx.x / (tpr * tpr);
    int tt = blockIdx.x % (tpr * tpr);
    int y0 = (tt / tpr) * 16, x0 = (tt % tpr) * 16;
    const int tid = threadIdx.x;
    const int wv = tid >> 6, lane = tid & 63;
    const int lc = lane & 15, kg = lane >> 4;

    // per-lane column offsets (units: shorts) for kx = 0..2
    int sxo[3];
#pragma unroll
    for (int kx = 0; kx < 3; ++kx) {
        int gx = x0 + lc + kx - 1;                 // in [-1, H]
        sxo[kx] = ((gx >> UP) + 1) * 64;
    }
    // row bases for gy = y0 + 2wv + r - 1, r = m + ky in 0..3
    size_t rowb[4];
#pragma unroll
    for (int r = 0; r < 4; ++r) {
        int gy = y0 + 2 * wv + r - 1;
        rowb[r] = (size_t)(b * pitch + (gy >> UP) + 1) * (pitch * 64);
    }

    f32x4 acc[2][4];
#pragma unroll
    for (int m = 0; m < 2; ++m)
#pragma unroll
        for (int n = 0; n < 4; ++n) acc[m][n] = f32x4{0.f, 0.f, 0.f, 0.f};

    for (int t = 0; t < 9; ++t) {
        int ky = t / 3, kx = t - ky * 3;
#pragma unroll
        for (int ch = 0; ch < 2; ++ch) {
            int aoff = sxo[kx] + ch * 32 + kg * 8;
            short8 ah0 = *(const short8*)&ahi[rowb[ky]     + aoff];
            short8 ah1 = *(const short8*)&ahi[rowb[ky + 1] + aoff];
            short8 al0 = *(const short8*)&alo[rowb[ky]     + aoff];
            short8 al1 = *(const short8*)&alo[rowb[ky + 1] + aoff];
#pragma unroll
            for (int n = 0; n < 4; ++n) {
                int wb = (t * 64 + n * 16 + lc) * 64 + ch * 32 + kg * 8;
                short8 bh = *(const short8*)&whi[wb];
                short8 bl = *(const short8*)&wlo[wb];
                acc[0][n] = __builtin_amdgcn_mfma_f32_16x16x32_bf16(ah0, bh, acc[0][n], 0, 0, 0);
                acc[0][n] = __builtin_amdgcn_mfma_f32_16x16x32_bf16(ah0, bl, acc[0][n], 0, 0, 0);
                acc[0][n] = __builtin_amdgcn_mfma_f32_16x16x32_bf16(al0, bh, acc[0][n], 0, 0, 0);
                acc[1][n] = __builtin_amdgcn_mfma_f32_16x16x32_bf16(ah1, bh, acc[1][n], 0, 0, 0);
                acc[1][n] = __builtin_amdgcn_mfma_f32_16x16x32_bf16(ah1, bl, acc[1][n], 0, 0, 0);
                acc[1][n] = __builtin_amdgcn_mfma_f32_16x16x32_bf16(al1, bh, acc[1][n], 0, 0, 0);
            }
        }
    }

    // epilogue: D col(lane&15)=co frag idx, row(kg*4+reg)=pixel-x (verified r4)
    if (NHWC_OUT) {
        const int opitch = H + 2;
#pragma unroll
        for (int n = 0; n < 4; ++n) {
            int co = n * 16 + lc;
            float bv = bias[co];
#pragma unroll
            for (int m = 0; m < 2; ++m) {
                int row = y0 + 2 * wv + m, cb = x0 + kg * 4;
                f32x4 v = acc[m][n];
#pragma unroll
                for (int j = 0; j < 4; ++j) {
                    float val = fmaxf(v[j] + bv, 0.f);
                    unsigned short h, l;
                    bf16split(val, h, l);
                    size_t a = ((size_t)(b * opitch + row + 1) * opitch + cb + j + 1) * 64 + co;
                    ohi[a] = h; olo[a] = l;
                }
            }
        }
    } else {
#pragma unroll
        for (int n = 0; n < 4; ++n) {
            int co = n * 16 + lc;
            float bv = bias[co];
#pragma unroll
            for (int m = 0; m < 2; ++m) {
                int row = y0 + 2 * wv + m, cb = x0 + kg * 4;
                f32x4 v = acc[m][n], res;
                res.x = fmaxf(v.x + bv, 0.f);
                res.y = fmaxf(v.y + bv, 0.f);
                res.z = fmaxf(v.z + bv, 0.f);
                res.w = fmaxf(v.w + bv, 0.f);
                *(f32x4*)&outf[((size_t)(b * 64 + co) * H + row) * H + cb] = res;
            }
        }
    }
}

// ---- avgpool2: (64,64,32,32) -> (64,64,16,16) NCHW f32 ----
__global__ void pool_kernel(const float* __restrict__ in, float* __restrict__ out, int Ho)
{
    int idx = blockIdx.x * 256 + threadIdx.x;
    int n = 64 * 64 * Ho * Ho;
    if (idx >= n) return;
    int x = idx % Ho; int y = (idx / Ho) % Ho; int p = idx / (Ho * Ho);
    int Hi = 2 * Ho;
    const float* ip = in + (size_t)p * Hi * Hi;
    float s = ip[(2 * y) * Hi + 2 * x] + ip[(2 * y) * Hi + 2 * x + 1]
            + ip[(2 * y + 1) * Hi + 2 * x] + ip[(2 * y + 1) * Hi + 2 * x + 1];
    out[idx] = s * 0.25f;
}

// ---- enc conv: 64->1, 16x16, relu -> x (64,256) ----
__global__ __launch_bounds__(256) void enc_kernel(
    const float* __restrict__ in, const float* __restrict__ w,
    const float* __restrict__ bias, float* __restrict__ xout)
{
    int b = blockIdx.x; int tid = threadIdx.x;
    int y = tid >> 4, x = tid & 15;
    __shared__ float sE[8192];
    double acc = 0.0;
    for (int ch = 0; ch < 2; ++ch) {
        __syncthreads();
        for (int k = tid; k < 8192; k += 256) sE[k] = in[(size_t)b * 16384 + ch * 8192 + k];
        __syncthreads();
        for (int cip = 0; cip < 32; ++cip) {
            int ci = ch * 32 + cip;
#pragma unroll
            for (int ky = 0; ky < 3; ++ky) {
                int gy = y + ky - 1;
                if ((unsigned)gy >= 16u) continue;
#pragma unroll
                for (int kx = 0; kx < 3; ++kx) {
                    int gx = x + kx - 1;
                    if ((unsigned)gx >= 16u) continue;
                    acc = fma((double)w[ci * 9 + ky * 3 + kx],
                              (double)sE[cip * 256 + gy * 16 + gx], acc);
                }
            }
        }
    }
    float v = (float)(acc + (double)bias[0]);
    xout[b * 256 + tid] = fmaxf(v, 0.f);
}

// ---- LSTM (zero state): h = sig(zo)*tanh(sig(zi)*tanh(zg)) ----
__global__ __launch_bounds__(256) void lstm_kernel(
    const float* __restrict__ x, const float* __restrict__ wx,
    const float* __restrict__ bl, float* __restrict__ h)
{
    int b = blockIdx.x, j = threadIdx.x;
    __shared__ float sx[256];
    sx[j] = x[b * 256 + j];
    __syncthreads();
    double zi = 0, zg = 0, zo = 0;
    for (int d = 0; d < 256; ++d) {
        double xv = (double)sx[d];
        const float* row = wx + (size_t)d * 1024;
        zi = fma(xv, (double)row[j], zi);
        zg = fma(xv, (double)row[512 + j], zg);
        zo = fma(xv, (double)row[768 + j], zo);
    }
    float zif = (float)(zi + (double)bl[j]);
    float zgf = (float)(zg + (double)bl[512 + j]);
    float zof = (float)(zo + (double)bl[768 + j]);
    double c = (1.0 / (1.0 + exp(-(double)zif))) * tanh((double)zgf);
    float cf = (float)c;
    double hh = (1.0 / (1.0 + exp(-(double)zof))) * tanh((double)cf);
    h[b * 256 + j] = (float)hh;
}

// ---- rowsums of w_out reads-block ----
__global__ void rowsum_kernel(const float* __restrict__ w_out, double* __restrict__ rs)
{
    int r = blockIdx.x, m = threadIdx.x;
    double s = 0;
    for (int d = 0; d < 256; ++d) s += (double)w_out[(size_t)(256 + r * 256 + d) * 256 + m];
    rs[r * 256 + m] = s;
}

// ---- read-head scalar rv[b,r] ----
__global__ __launch_bounds__(256) void gamma_kernel(
    const float* __restrict__ h, const float* __restrict__ w_param,
    const float* __restrict__ b_param, double* __restrict__ rv)
{
    int b = blockIdx.x, t = threadIdx.x;
    __shared__ double sp[3][256];
    float hv = h[b * 256 + t];
#pragma unroll
    for (int r = 0; r < 3; ++r)
        sp[r][t] = (double)hv * (double)w_param[(size_t)t * 3108 + r * 262 + 261];
    __syncthreads();
    if (t < 3) {
        double s = 0;
        for (int d = 0; d < 256; ++d) s += sp[t][d];
        float pf = (float)(s + (double)b_param[t * 262 + 261]);
        pf = fminf(fmaxf(pf, -20.f), 20.f);
        double gamma = log1p(exp((double)pf)) + 1.0;
        double q = pow(0.015625 + 1e-16, gamma);
        double wv = q / (64.0 * q + 1e-8);
        rv[b * 3 + t] = wv * 64.0 * 1e-6;
    }
}

// ---- ntm out: clip(h@w_out[:256] + b_out + sum_r rv_r*rs_r, +-20) ----
__global__ __launch_bounds__(256) void ntmout_kernel(
    const float* __restrict__ h, const float* __restrict__ w_out,
    const float* __restrict__ b_out, const double* __restrict__ rv,
    const double* __restrict__ rs, float* __restrict__ out)
{
    int b = blockIdx.x, m = threadIdx.x;
    __shared__ float sh[256];
    __shared__ double srv[3];
    sh[m] = h[b * 256 + m];
    if (m < 3) srv[m] = rv[b * 3 + m];
    __syncthreads();
    double acc = 0;
    for (int d = 0; d < 256; ++d)
        acc = fma((double)sh[d], (double)w_out[(size_t)d * 256 + m], acc);
    acc += (double)b_out[m];
#pragma unroll
    for (int r = 0; r < 3; ++r) acc += srv[r] * rs[r * 256 + m];
    acc = fmin(fmax(acc, -20.0), 20.0);
    out[b * 256 + m] = (float)acc;
}

// ---- conv2: 1->64 3x3 SAME + relu, ntm (64,16,16) -> A3 NHWC hi/lo interior ----
__global__ __launch_bounds__(256) void conv2_kernel(
    const float* __restrict__ in, const float* __restrict__ w,
    const float* __restrict__ bias,
    unsigned short* __restrict__ ohi, unsigned short* __restrict__ olo)
{
    int idx = blockIdx.x * 256 + threadIdx.x;      // 64*16*16*64 = 1,048,576
    int co = idx & 63, x = (idx >> 6) & 15, y = (idx >> 10) & 15, b = idx >> 14;
    float acc = bias[co];
    const float* ip = in + (size_t)b * 256;
#pragma unroll
    for (int ky = 0; ky < 3; ++ky) {
        int gy = y + ky - 1;
        if ((unsigned)gy >= 16u) continue;
#pragma unroll
        for (int kx = 0; kx < 3; ++kx) {
            int gx = x + kx - 1;
            if ((unsigned)gx >= 16u) continue;
            acc = fmaf(w[co * 9 + ky * 3 + kx], ip[gy * 16 + gx], acc);
        }
    }
    unsigned short h, l;
    bf16split(fmaxf(acc, 0.f), h, l);
    size_t a = ((size_t)(b * 18 + y + 1) * 18 + x + 1) * 64 + co;
    ohi[a] = h; olo[a] = l;
}

extern "C" void kernel_launch(void* const* d_in, const int* in_sizes, int n_in,
                              void* d_out, int out_size, void* d_ws, size_t ws_size,
                              hipStream_t stream)
{
    const float* inputs   = (const float*)d_in[0];
    const float* w_conv0  = (const float*)d_in[1];
    const float* b_conv0  = (const float*)d_in[2];
    const float* w_conv1  = (const float*)d_in[3];
    const float* b_conv1  = (const float*)d_in[4];
    const float* w_enc    = (const float*)d_in[5];
    const float* b_enc    = (const float*)d_in[6];
    const float* w_conv2  = (const float*)d_in[7];
    const float* b_conv2  = (const float*)d_in[8];
    const float* w_conv3  = (const float*)d_in[9];
    const float* b_conv3  = (const float*)d_in[10];
    const float* w_conv4  = (const float*)d_in[11];
    const float* b_conv4  = (const float*)d_in[12];
    const float* w_lstm_x = (const float*)d_in[13];
    // d_in[14] = w_lstm_h : dead (h0 == 0)
    const float* b_lstm   = (const float*)d_in[15];
    const float* w_param  = (const float*)d_in[16];
    const float* b_param  = (const float*)d_in[17];
    const float* w_out_   = (const float*)d_in[18];
    const float* b_out_   = (const float*)d_in[19];

    char* ws = (char*)d_ws;
    unsigned short* a1h = (unsigned short*)(ws + OFF_A1H);
    unsigned short* a1l = (unsigned short*)(ws + OFF_A1L);
    float*  t1  = (float*)(ws + OFF_T1);
    float*  t2  = (float*)(ws + OFF_T2);
    unsigned short* a3h = (unsigned short*)(ws + OFF_A3H);
    unsigned short* a3l = (unsigned short*)(ws + OFF_A3L);
    // A4 reuses A1 (same shape/pitch; a1 dead after conv1; ring stays zero)
    unsigned short* a4h = a1h;
    unsigned short* a4l = a1l;
    unsigned short* whi1 = (unsigned short*)(ws + OFF_W1); unsigned short* wlo1 = whi1 + 36864;
    unsigned short* whi3 = (unsigned short*)(ws + OFF_W3); unsigned short* wlo3 = whi3 + 36864;
    unsigned short* whi4 = (unsigned short*)(ws + OFF_W4); unsigned short* wlo4 = whi4 + 36864;
    float*  xE  = (float*)(ws + OFF_XE);
    float*  h   = (float*)(ws + OFF_H);
    double* rv  = (double*)(ws + OFF_RV);
    double* rs  = (double*)(ws + OFF_RS);
    float*  ntm = (float*)(ws + OFF_N);

    wprep_kernel<<<144, 256, 0, stream>>>(w_conv1, whi1, wlo1);
    wprep_kernel<<<144, 256, 0, stream>>>(w_conv3, whi3, wlo3);
    wprep_kernel<<<144, 256, 0, stream>>>(w_conv4, whi4, wlo4);

    halo_zero_kernel<<<2112, 256, 0, stream>>>(a1h, a1l, 32);   // also serves conv4 input
    halo_zero_kernel<<<1088, 256, 0, stream>>>(a3h, a3l, 16);

    conv0_pool_kernel<<<16384, 256, 0, stream>>>(inputs, w_conv0, b_conv0, a1h, a1l);
    conv_mfma_kernel<0, false><<<256, 512, 0, stream>>>(
        a1h, a1l, whi1, wlo1, b_conv1, t1, nullptr, nullptr, 32);
    pool_kernel<<<4096, 256, 0, stream>>>(t1, t2, 16);
    enc_kernel<<<64, 256, 0, stream>>>(t2, w_enc, b_enc, xE);

    lstm_kernel<<<64, 256, 0, stream>>>(xE, w_lstm_x, b_lstm, h);
    rowsum_kernel<<<3, 256, 0, stream>>>(w_out_, rs);
    gamma_kernel<<<64, 256, 0, stream>>>(h, w_param, b_param, rv);
    ntmout_kernel<<<64, 256, 0, stream>>>(h, w_out_, b_out_, rv, rs, ntm);

    conv2_kernel<<<4096, 256, 0, stream>>>(ntm, w_conv2, b_conv2, a3h, a3l);
    conv_mfma_kernel<1, true><<<256, 512, 0, stream>>>(
        a3h, a3l, whi3, wlo3, b_conv3, nullptr, a4h, a4l, 32);
    conv_mfma_kernel<1, false><<<1024, 512, 0, stream>>>(
        a4h, a4l, whi4, wlo4, b_conv4, (float*)d_out, nullptr, nullptr, 64);
}

// Round 7
// 267.131 us; speedup vs baseline: 3.6269x; 1.6108x over previous
//
#include <hip/hip_runtime.h>
#include <hip/hip_bf16.h>

// ============================================================================
// Round 7: kill address divergence in conv_mfma (round-6: MfmaUtil 12%,
// VALUBusy 7%, all loads lane-stride 128B -> 16 cache lines per wave-load).
//  - Weights pre-packed in MFMA fragment order [t][ch][n][lane][8] -> every
//    B load is 1KB contiguous per wave (coalesced).
//  - A tile staged in LDS (coalesced 128B/pixel rows), fragments read via
//    ds_read_b128 with XOR swizzle (idx ^= (pix&7)<<3) -> conflict-free.
//    UP=1 tile: 25.6KB -> 4 blocks/CU; UP=0: 83KB (1 block/CU, grid=1/CU).
//  - <UP,H,NHWC_OUT> templates: all index math compile-time, no scratch.
// Numerics unchanged: 3-pass split-bf16, floor 3.81e-6 vs 2.41e-5 threshold.
// ============================================================================

typedef __attribute__((ext_vector_type(8))) short short8;
typedef __attribute__((ext_vector_type(4))) float f32x4;

// ---- workspace layout (bytes) ----
static const size_t OFF_A1H = 0;                       // A1/A4 NHWC hi (B,34,34,64)
static const size_t OFF_A1L = 9469952;                 // -> end 18,939,904
static const size_t OFF_T1  = 18939904;                // t1 conv1 out NCHW f32 16MB
static const size_t OFF_T2  = 35717120;                // t2 pool1 out NCHW f32 4MB
static const size_t OFF_A3H = 39911424;                // conv3 input NHWC (B,18,18,64)
static const size_t OFF_A3L = 42565632;                // -> end 45,219,840
static const size_t OFF_W1  = 45219840;                // packed whi+wlo 147,456 B/layer
static const size_t OFF_W3  = 45367296;
static const size_t OFF_W4  = 45514752;
static const size_t OFF_XE  = 45662208;                // xE (64,256) f32
static const size_t OFF_H   = 45727744;                // h  (64,256) f32
static const size_t OFF_RV  = 45793280;                // rv (64,3) f64
static const size_t OFF_RS  = 45794816;                // rs (3,256) f64
static const size_t OFF_N   = 45800960;                // ntm (64,256) f32

__device__ inline void bf16split(float v, unsigned short& h, unsigned short& l) {
    __hip_bfloat16 hb = __float2bfloat16(v);
    float hf = __bfloat162float(hb);
    __hip_bfloat16 lb = __float2bfloat16(v - hf);
    h = __builtin_bit_cast(unsigned short, hb);
    l = __builtin_bit_cast(unsigned short, lb);
}

// ---- weight prep: (co,ci,3,3) f32 -> fragment-packed hi/lo ----
// pack idx s = (((t*2+ch)*4+n)*64 + lane)*8 + j ; lane=(kg<<4)|lc
// co = n*16+lc ; ci = ch*32 + kg*8 + j ; value = w[(co*64+ci)*9 + t]
__global__ void wprep_kernel(const float* __restrict__ w,
                             unsigned short* __restrict__ whi,
                             unsigned short* __restrict__ wlo)
{
    int s = blockIdx.x * 256 + threadIdx.x;
    if (s >= 36864) return;
    int j  = s & 7;
    int ln = (s >> 3) & 63;
    int n  = (s >> 9) & 3;
    int ch = (s >> 11) & 1;
    int t  = s >> 12;
    int lc = ln & 15, kg = ln >> 4;
    int co = n * 16 + lc;
    int ci = ch * 32 + kg * 8 + j;
    unsigned short h, l;
    bf16split(w[(co * 64 + ci) * 9 + t], h, l);
    whi[s] = h; wlo[s] = l;
}

// ---- zero the 1-px halo ring of an NHWC (B,S+2,S+2,64) hi/lo pair ----
__global__ void halo_zero_kernel(unsigned short* __restrict__ hi,
                                 unsigned short* __restrict__ lo, int S)
{
    int P = S + 2, ring = 4 * S + 4;
    int idx = blockIdx.x * 256 + threadIdx.x;
    if (idx >= 64 * ring * 64) return;
    int co = idx & 63;
    int cell = (idx >> 6) % ring;
    int b = (idx >> 6) / ring;
    int y, x;
    if (cell < P)            { y = 0;     x = cell; }
    else if (cell < 2 * P)   { y = P - 1; x = cell - P; }
    else { int c2 = cell - 2 * P; y = 1 + (c2 >> 1); x = (c2 & 1) ? P - 1 : 0; }
    size_t a = ((size_t)(b * P + y) * P + x) * 64 + co;
    hi[a] = 0; lo[a] = 0;
}

// ---- fused conv0 (1->64, 3x3 SAME, relu) + avgpool2 -> A1 NHWC hi/lo ----
__global__ __launch_bounds__(256) void conv0_pool_kernel(
    const float* __restrict__ in, const float* __restrict__ w,
    const float* __restrict__ bias,
    unsigned short* __restrict__ ohi, unsigned short* __restrict__ olo)
{
    int idx = blockIdx.x * 256 + threadIdx.x;      // 64*32*32*64 = 4,194,304
    int co = idx & 63, x = (idx >> 6) & 31, y = (idx >> 11) & 31, b = idx >> 16;
    float w9[9];
#pragma unroll
    for (int t = 0; t < 9; ++t) w9[t] = w[co * 9 + t];
    float bv = bias[co];
    const float* ip = in + (size_t)b * 4096;
    float p[4][4];
#pragma unroll
    for (int r = 0; r < 4; ++r) {
        int gy = 2 * y - 1 + r;
#pragma unroll
        for (int c = 0; c < 4; ++c) {
            int gx = 2 * x - 1 + c;
            float v = 0.f;
            if ((unsigned)gy < 64u && (unsigned)gx < 64u) v = ip[gy * 64 + gx];
            p[r][c] = v;
        }
    }
    float s4 = 0.f;
#pragma unroll
    for (int dy = 0; dy < 2; ++dy)
#pragma unroll
        for (int dx = 0; dx < 2; ++dx) {
            float a = bv;
#pragma unroll
            for (int ky = 0; ky < 3; ++ky)
#pragma unroll
                for (int kx = 0; kx < 3; ++kx)
                    a = fmaf(w9[ky * 3 + kx], p[dy + ky][dx + kx], a);
            s4 += fmaxf(a, 0.f);
        }
    unsigned short h, l;
    bf16split(s4 * 0.25f, h, l);
    size_t a = ((size_t)(b * 34 + y + 1) * 34 + x + 1) * 64 + co;
    ohi[a] = h; olo[a] = l;
}

// ---- LDS-staged MFMA implicit-GEMM 64->64 3x3 SAME conv + relu ----
template <int UP, int H, bool NHWC_OUT>
__global__ __launch_bounds__(512) void conv_mfma_kernel(
    const unsigned short* __restrict__ ahi, const unsigned short* __restrict__ alo,
    const unsigned short* __restrict__ whiP, const unsigned short* __restrict__ wloP,
    const float* __restrict__ bias,
    float* __restrict__ outf, unsigned short* __restrict__ ohi,
    unsigned short* __restrict__ olo)
{
    constexpr int SRC   = H >> UP;
    constexpr int PITCH = SRC + 2;
    constexpr int TPR   = H / 16;
    constexpr int W     = UP ? 10 : 18;    // src-region width incl halo
    constexpr int NPX   = W * W;

    int b  = blockIdx.x / (TPR * TPR);
    int tt = blockIdx.x % (TPR * TPR);
    int y0 = (tt / TPR) * 16, x0 = (tt % TPR) * 16;
    const int tid = threadIdx.x;
    const int wv = tid >> 6, lane = tid & 63;
    const int lc = lane & 15, kg = lane >> 4;

    __shared__ unsigned short sAhi[NPX * 64];
    __shared__ unsigned short sAlo[NPX * 64];

    const int r0 = ((y0 - 1) >> UP) + 1;   // padded-coord region start
    const int c0 = ((x0 - 1) >> UP) + 1;

    // stage: coalesced 16B chunks, XOR-swizzled destination
    for (int c = tid; c < NPX * 8; c += 512) {
        int pix = c >> 3, sub = c & 7;
        int py = pix / W, px = pix - py * W;
        size_t g = ((size_t)(b * PITCH + r0 + py) * PITCH + (c0 + px)) * 64 + sub * 8;
        int l = (pix * 64 + sub * 8) ^ ((pix & 7) << 3);
        *(short8*)&sAhi[l] = *(const short8*)&ahi[g];
        *(short8*)&sAlo[l] = *(const short8*)&alo[g];
    }
    __syncthreads();

    // per-lane local pixel coords
    int lxv[3], lyv[4];
#pragma unroll
    for (int kx = 0; kx < 3; ++kx)
        lxv[kx] = (((x0 + lc + kx - 1) >> UP) + 1) - c0;
#pragma unroll
    for (int r = 0; r < 4; ++r)
        lyv[r] = (((y0 + 2 * wv + r - 1) >> UP) + 1) - r0;

    f32x4 acc[2][4];
#pragma unroll
    for (int m = 0; m < 2; ++m)
#pragma unroll
        for (int n = 0; n < 4; ++n) acc[m][n] = f32x4{0.f, 0.f, 0.f, 0.f};

#pragma unroll
    for (int ky = 0; ky < 3; ++ky) {
#pragma unroll
        for (int kx = 0; kx < 3; ++kx) {
            const int t = ky * 3 + kx;
#pragma unroll
            for (int ch = 0; ch < 2; ++ch) {
                int p0 = lyv[ky]     * W + lxv[kx];
                int p1 = lyv[ky + 1] * W + lxv[kx];
                int i0 = (p0 * 64 + ch * 32 + kg * 8) ^ ((p0 & 7) << 3);
                int i1 = (p1 * 64 + ch * 32 + kg * 8) ^ ((p1 & 7) << 3);
                short8 ah0 = *(const short8*)&sAhi[i0];
                short8 ah1 = *(const short8*)&sAhi[i1];
                short8 al0 = *(const short8*)&sAlo[i0];
                short8 al1 = *(const short8*)&sAlo[i1];
#pragma unroll
                for (int n = 0; n < 4; ++n) {
                    int wb = (((t * 2 + ch) * 4 + n) * 64 + lane) * 8;  // coalesced
                    short8 bh = *(const short8*)&whiP[wb];
                    short8 bl = *(const short8*)&wloP[wb];
                    acc[0][n] = __builtin_amdgcn_mfma_f32_16x16x32_bf16(ah0, bh, acc[0][n], 0, 0, 0);
                    acc[0][n] = __builtin_amdgcn_mfma_f32_16x16x32_bf16(ah0, bl, acc[0][n], 0, 0, 0);
                    acc[0][n] = __builtin_amdgcn_mfma_f32_16x16x32_bf16(al0, bh, acc[0][n], 0, 0, 0);
                    acc[1][n] = __builtin_amdgcn_mfma_f32_16x16x32_bf16(ah1, bh, acc[1][n], 0, 0, 0);
                    acc[1][n] = __builtin_amdgcn_mfma_f32_16x16x32_bf16(ah1, bl, acc[1][n], 0, 0, 0);
                    acc[1][n] = __builtin_amdgcn_mfma_f32_16x16x32_bf16(al1, bh, acc[1][n], 0, 0, 0);
                }
            }
        }
    }

    // epilogue: D col(lane&15)=co frag idx, row(kg*4+reg)=pixel-x (verified r4)
    if (NHWC_OUT) {
        const int opitch = H + 2;
#pragma unroll
        for (int n = 0; n < 4; ++n) {
            int co = n * 16 + lc;
            float bv = bias[co];
#pragma unroll
            for (int m = 0; m < 2; ++m) {
                int row = y0 + 2 * wv + m, cb = x0 + kg * 4;
                f32x4 v = acc[m][n];
#pragma unroll
                for (int j = 0; j < 4; ++j) {
                    float val = fmaxf(v[j] + bv, 0.f);
                    unsigned short h, l;
                    bf16split(val, h, l);
                    size_t a = ((size_t)(b * opitch + row + 1) * opitch + cb + j + 1) * 64 + co;
                    ohi[a] = h; olo[a] = l;
                }
            }
        }
    } else {
#pragma unroll
        for (int n = 0; n < 4; ++n) {
            int co = n * 16 + lc;
            float bv = bias[co];
#pragma unroll
            for (int m = 0; m < 2; ++m) {
                int row = y0 + 2 * wv + m, cb = x0 + kg * 4;
                f32x4 v = acc[m][n], res;
                res.x = fmaxf(v.x + bv, 0.f);
                res.y = fmaxf(v.y + bv, 0.f);
                res.z = fmaxf(v.z + bv, 0.f);
                res.w = fmaxf(v.w + bv, 0.f);
                *(f32x4*)&outf[((size_t)(b * 64 + co) * H + row) * H + cb] = res;
            }
        }
    }
}

// ---- avgpool2: (64,64,32,32) -> (64,64,16,16) NCHW f32 ----
__global__ void pool_kernel(const float* __restrict__ in, float* __restrict__ out, int Ho)
{
    int idx = blockIdx.x * 256 + threadIdx.x;
    int n = 64 * 64 * Ho * Ho;
    if (idx >= n) return;
    int x = idx % Ho; int y = (idx / Ho) % Ho; int p = idx / (Ho * Ho);
    int Hi = 2 * Ho;
    const float* ip = in + (size_t)p * Hi * Hi;
    float s = ip[(2 * y) * Hi + 2 * x] + ip[(2 * y) * Hi + 2 * x + 1]
            + ip[(2 * y + 1) * Hi + 2 * x] + ip[(2 * y + 1) * Hi + 2 * x + 1];
    out[idx] = s * 0.25f;
}

// ---- enc conv: 64->1, 16x16, relu -> x (64,256) ----
__global__ __launch_bounds__(256) void enc_kernel(
    const float* __restrict__ in, const float* __restrict__ w,
    const float* __restrict__ bias, float* __restrict__ xout)
{
    int b = blockIdx.x; int tid = threadIdx.x;
    int y = tid >> 4, x = tid & 15;
    __shared__ float sE[8192];
    double acc = 0.0;
    for (int ch = 0; ch < 2; ++ch) {
        __syncthreads();
        for (int k = tid; k < 8192; k += 256) sE[k] = in[(size_t)b * 16384 + ch * 8192 + k];
        __syncthreads();
        for (int cip = 0; cip < 32; ++cip) {
            int ci = ch * 32 + cip;
#pragma unroll
            for (int ky = 0; ky < 3; ++ky) {
                int gy = y + ky - 1;
                if ((unsigned)gy >= 16u) continue;
#pragma unroll
                for (int kx = 0; kx < 3; ++kx) {
                    int gx = x + kx - 1;
                    if ((unsigned)gx >= 16u) continue;
                    acc = fma((double)w[ci * 9 + ky * 3 + kx],
                              (double)sE[cip * 256 + gy * 16 + gx], acc);
                }
            }
        }
    }
    float v = (float)(acc + (double)bias[0]);
    xout[b * 256 + tid] = fmaxf(v, 0.f);
}

// ---- LSTM (zero state): h = sig(zo)*tanh(sig(zi)*tanh(zg)) ----
__global__ __launch_bounds__(256) void lstm_kernel(
    const float* __restrict__ x, const float* __restrict__ wx,
    const float* __restrict__ bl, float* __restrict__ h)
{
    int b = blockIdx.x, j = threadIdx.x;
    __shared__ float sx[256];
    sx[j] = x[b * 256 + j];
    __syncthreads();
    double zi = 0, zg = 0, zo = 0;
    for (int d = 0; d < 256; ++d) {
        double xv = (double)sx[d];
        const float* row = wx + (size_t)d * 1024;
        zi = fma(xv, (double)row[j], zi);
        zg = fma(xv, (double)row[512 + j], zg);
        zo = fma(xv, (double)row[768 + j], zo);
    }
    float zif = (float)(zi + (double)bl[j]);
    float zgf = (float)(zg + (double)bl[512 + j]);
    float zof = (float)(zo + (double)bl[768 + j]);
    double c = (1.0 / (1.0 + exp(-(double)zif))) * tanh((double)zgf);
    float cf = (float)c;
    double hh = (1.0 / (1.0 + exp(-(double)zof))) * tanh((double)cf);
    h[b * 256 + j] = (float)hh;
}

// ---- rowsums of w_out reads-block ----
__global__ void rowsum_kernel(const float* __restrict__ w_out, double* __restrict__ rs)
{
    int r = blockIdx.x, m = threadIdx.x;
    double s = 0;
    for (int d = 0; d < 256; ++d) s += (double)w_out[(size_t)(256 + r * 256 + d) * 256 + m];
    rs[r * 256 + m] = s;
}

// ---- read-head scalar rv[b,r] ----
__global__ __launch_bounds__(256) void gamma_kernel(
    const float* __restrict__ h, const float* __restrict__ w_param,
    const float* __restrict__ b_param, double* __restrict__ rv)
{
    int b = blockIdx.x, t = threadIdx.x;
    __shared__ double sp[3][256];
    float hv = h[b * 256 + t];
#pragma unroll
    for (int r = 0; r < 3; ++r)
        sp[r][t] = (double)hv * (double)w_param[(size_t)t * 3108 + r * 262 + 261];
    __syncthreads();
    if (t < 3) {
        double s = 0;
        for (int d = 0; d < 256; ++d) s += sp[t][d];
        float pf = (float)(s + (double)b_param[t * 262 + 261]);
        pf = fminf(fmaxf(pf, -20.f), 20.f);
        double gamma = log1p(exp((double)pf)) + 1.0;
        double q = pow(0.015625 + 1e-16, gamma);
        double wv = q / (64.0 * q + 1e-8);
        rv[b * 3 + t] = wv * 64.0 * 1e-6;
    }
}

// ---- ntm out: clip(h@w_out[:256] + b_out + sum_r rv_r*rs_r, +-20) ----
__global__ __launch_bounds__(256) void ntmout_kernel(
    const float* __restrict__ h, const float* __restrict__ w_out,
    const float* __restrict__ b_out, const double* __restrict__ rv,
    const double* __restrict__ rs, float* __restrict__ out)
{
    int b = blockIdx.x, m = threadIdx.x;
    __shared__ float sh[256];
    __shared__ double srv[3];
    sh[m] = h[b * 256 + m];
    if (m < 3) srv[m] = rv[b * 3 + m];
    __syncthreads();
    double acc = 0;
    for (int d = 0; d < 256; ++d)
        acc = fma((double)sh[d], (double)w_out[(size_t)d * 256 + m], acc);
    acc += (double)b_out[m];
#pragma unroll
    for (int r = 0; r < 3; ++r) acc += srv[r] * rs[r * 256 + m];
    acc = fmin(fmax(acc, -20.0), 20.0);
    out[b * 256 + m] = (float)acc;
}

// ---- conv2: 1->64 3x3 SAME + relu, ntm (64,16,16) -> A3 NHWC hi/lo ----
__global__ __launch_bounds__(256) void conv2_kernel(
    const float* __restrict__ in, const float* __restrict__ w,
    const float* __restrict__ bias,
    unsigned short* __restrict__ ohi, unsigned short* __restrict__ olo)
{
    int idx = blockIdx.x * 256 + threadIdx.x;      // 64*16*16*64 = 1,048,576
    int co = idx & 63, x = (idx >> 6) & 15, y = (idx >> 10) & 15, b = idx >> 14;
    float acc = bias[co];
    const float* ip = in + (size_t)b * 256;
#pragma unroll
    for (int ky = 0; ky < 3; ++ky) {
        int gy = y + ky - 1;
        if ((unsigned)gy >= 16u) continue;
#pragma unroll
        for (int kx = 0; kx < 3; ++kx) {
            int gx = x + kx - 1;
            if ((unsigned)gx >= 16u) continue;
            acc = fmaf(w[co * 9 + ky * 3 + kx], ip[gy * 16 + gx], acc);
        }
    }
    unsigned short h, l;
    bf16split(fmaxf(acc, 0.f), h, l);
    size_t a = ((size_t)(b * 18 + y + 1) * 18 + x + 1) * 64 + co;
    ohi[a] = h; olo[a] = l;
}

extern "C" void kernel_launch(void* const* d_in, const int* in_sizes, int n_in,
                              void* d_out, int out_size, void* d_ws, size_t ws_size,
                              hipStream_t stream)
{
    const float* inputs   = (const float*)d_in[0];
    const float* w_conv0  = (const float*)d_in[1];
    const float* b_conv0  = (const float*)d_in[2];
    const float* w_conv1  = (const float*)d_in[3];
    const float* b_conv1  = (const float*)d_in[4];
    const float* w_enc    = (const float*)d_in[5];
    const float* b_enc    = (const float*)d_in[6];
    const float* w_conv2  = (const float*)d_in[7];
    const float* b_conv2  = (const float*)d_in[8];
    const float* w_conv3  = (const float*)d_in[9];
    const float* b_conv3  = (const float*)d_in[10];
    const float* w_conv4  = (const float*)d_in[11];
    const float* b_conv4  = (const float*)d_in[12];
    const float* w_lstm_x = (const float*)d_in[13];
    // d_in[14] = w_lstm_h : dead (h0 == 0)
    const float* b_lstm   = (const float*)d_in[15];
    const float* w_param  = (const float*)d_in[16];
    const float* b_param  = (const float*)d_in[17];
    const float* w_out_   = (const float*)d_in[18];
    const float* b_out_   = (const float*)d_in[19];

    char* ws = (char*)d_ws;
    unsigned short* a1h = (unsigned short*)(ws + OFF_A1H);
    unsigned short* a1l = (unsigned short*)(ws + OFF_A1L);
    float*  t1  = (float*)(ws + OFF_T1);
    float*  t2  = (float*)(ws + OFF_T2);
    unsigned short* a3h = (unsigned short*)(ws + OFF_A3H);
    unsigned short* a3l = (unsigned short*)(ws + OFF_A3L);
    // A4 reuses A1 (same shape/pitch; a1 dead after conv1; ring stays zero)
    unsigned short* a4h = a1h;
    unsigned short* a4l = a1l;
    unsigned short* whi1 = (unsigned short*)(ws + OFF_W1); unsigned short* wlo1 = whi1 + 36864;
    unsigned short* whi3 = (unsigned short*)(ws + OFF_W3); unsigned short* wlo3 = whi3 + 36864;
    unsigned short* whi4 = (unsigned short*)(ws + OFF_W4); unsigned short* wlo4 = whi4 + 36864;
    float*  xE  = (float*)(ws + OFF_XE);
    float*  h   = (float*)(ws + OFF_H);
    double* rv  = (double*)(ws + OFF_RV);
    double* rs  = (double*)(ws + OFF_RS);
    float*  ntm = (float*)(ws + OFF_N);

    wprep_kernel<<<144, 256, 0, stream>>>(w_conv1, whi1, wlo1);
    wprep_kernel<<<144, 256, 0, stream>>>(w_conv3, whi3, wlo3);
    wprep_kernel<<<144, 256, 0, stream>>>(w_conv4, whi4, wlo4);

    halo_zero_kernel<<<2112, 256, 0, stream>>>(a1h, a1l, 32);   // also serves conv4 input
    halo_zero_kernel<<<1088, 256, 0, stream>>>(a3h, a3l, 16);

    conv0_pool_kernel<<<16384, 256, 0, stream>>>(inputs, w_conv0, b_conv0, a1h, a1l);
    conv_mfma_kernel<0, 32, false><<<256, 512, 0, stream>>>(
        a1h, a1l, whi1, wlo1, b_conv1, t1, nullptr, nullptr);
    pool_kernel<<<4096, 256, 0, stream>>>(t1, t2, 16);
    enc_kernel<<<64, 256, 0, stream>>>(t2, w_enc, b_enc, xE);

    lstm_kernel<<<64, 256, 0, stream>>>(xE, w_lstm_x, b_lstm, h);
    rowsum_kernel<<<3, 256, 0, stream>>>(w_out_, rs);
    gamma_kernel<<<64, 256, 0, stream>>>(h, w_param, b_param, rv);
    ntmout_kernel<<<64, 256, 0, stream>>>(h, w_out_, b_out_, rv, rs, ntm);

    conv2_kernel<<<4096, 256, 0, stream>>>(ntm, w_conv2, b_conv2, a3h, a3l);
    conv_mfma_kernel<1, 32, true><<<256, 512, 0, stream>>>(
        a3h, a3l, whi3, wlo3, b_conv3, nullptr, a4h, a4l);
    conv_mfma_kernel<1, 64, false><<<1024, 512, 0, stream>>>(
        a4h, a4l, whi4, wlo4, b_conv4, (float*)d_out, nullptr, nullptr);
}

// Round 8
// 234.000 us; speedup vs baseline: 4.1404x; 1.1416x over previous
//
#include <hip/hip_runtime.h>
#include <hip/hip_bf16.h>

// ============================================================================
// Round 8: conv MFMA — B weights through LDS (double-buffered 8KB/slice).
// R7 analysis: conv4 at 61us vs 23us MFMA floor; 8 waves/block each re-read
// the full 144KB packed weight set from L1/L2 (~1.2GB L2 traffic/dispatch).
// Now one cooperative 512x16B load per k-iter stages the (t,ch) slice into
// LDS; waves ds_read it -> 8x less L2 traffic. One barrier/iter; hazard-safe
// via end-of-iter barrier ordering. Also: conv1/conv3/conv4 get distinct
// kernel names (wrappers over a __device__ body) for per-layer profiling.
// Numerics bit-identical: 3-pass split-bf16, floor 3.814697e-6.
// ============================================================================

typedef __attribute__((ext_vector_type(8))) short short8;
typedef __attribute__((ext_vector_type(4))) float f32x4;

// ---- workspace layout (bytes) ----
static const size_t OFF_A1H = 0;                       // A1/A4 NHWC hi (B,34,34,64)
static const size_t OFF_A1L = 9469952;                 // -> end 18,939,904
static const size_t OFF_T1  = 18939904;                // t1 conv1 out NCHW f32 16MB
static const size_t OFF_T2  = 35717120;                // t2 pool1 out NCHW f32 4MB
static const size_t OFF_A3H = 39911424;                // conv3 input NHWC (B,18,18,64)
static const size_t OFF_A3L = 42565632;                // -> end 45,219,840
static const size_t OFF_W1  = 45219840;                // packed whi+wlo 147,456 B/layer
static const size_t OFF_W3  = 45367296;
static const size_t OFF_W4  = 45514752;
static const size_t OFF_XE  = 45662208;                // xE (64,256) f32
static const size_t OFF_H   = 45727744;                // h  (64,256) f32
static const size_t OFF_RV  = 45793280;                // rv (64,3) f64
static const size_t OFF_RS  = 45794816;                // rs (3,256) f64
static const size_t OFF_N   = 45800960;                // ntm (64,256) f32

__device__ inline void bf16split(float v, unsigned short& h, unsigned short& l) {
    __hip_bfloat16 hb = __float2bfloat16(v);
    float hf = __bfloat162float(hb);
    __hip_bfloat16 lb = __float2bfloat16(v - hf);
    h = __builtin_bit_cast(unsigned short, hb);
    l = __builtin_bit_cast(unsigned short, lb);
}

// ---- weight prep: (co,ci,3,3) f32 -> fragment-packed hi/lo ----
// pack idx s = (((t*2+ch)*4+n)*64 + lane)*8 + j ; lane=(kg<<4)|lc
// co = n*16+lc ; ci = ch*32 + kg*8 + j ; value = w[(co*64+ci)*9 + t]
__global__ void wprep_kernel(const float* __restrict__ w,
                             unsigned short* __restrict__ whi,
                             unsigned short* __restrict__ wlo)
{
    int s = blockIdx.x * 256 + threadIdx.x;
    if (s >= 36864) return;
    int j  = s & 7;
    int ln = (s >> 3) & 63;
    int n  = (s >> 9) & 3;
    int ch = (s >> 11) & 1;
    int t  = s >> 12;
    int lc = ln & 15, kg = ln >> 4;
    int co = n * 16 + lc;
    int ci = ch * 32 + kg * 8 + j;
    unsigned short h, l;
    bf16split(w[(co * 64 + ci) * 9 + t], h, l);
    whi[s] = h; wlo[s] = l;
}

// ---- zero the 1-px halo ring of an NHWC (B,S+2,S+2,64) hi/lo pair ----
__global__ void halo_zero_kernel(unsigned short* __restrict__ hi,
                                 unsigned short* __restrict__ lo, int S)
{
    int P = S + 2, ring = 4 * S + 4;
    int idx = blockIdx.x * 256 + threadIdx.x;
    if (idx >= 64 * ring * 64) return;
    int co = idx & 63;
    int cell = (idx >> 6) % ring;
    int b = (idx >> 6) / ring;
    int y, x;
    if (cell < P)            { y = 0;     x = cell; }
    else if (cell < 2 * P)   { y = P - 1; x = cell - P; }
    else { int c2 = cell - 2 * P; y = 1 + (c2 >> 1); x = (c2 & 1) ? P - 1 : 0; }
    size_t a = ((size_t)(b * P + y) * P + x) * 64 + co;
    hi[a] = 0; lo[a] = 0;
}

// ---- fused conv0 (1->64, 3x3 SAME, relu) + avgpool2 -> A1 NHWC hi/lo ----
__global__ __launch_bounds__(256) void conv0_pool_kernel(
    const float* __restrict__ in, const float* __restrict__ w,
    const float* __restrict__ bias,
    unsigned short* __restrict__ ohi, unsigned short* __restrict__ olo)
{
    int idx = blockIdx.x * 256 + threadIdx.x;      // 64*32*32*64 = 4,194,304
    int co = idx & 63, x = (idx >> 6) & 31, y = (idx >> 11) & 31, b = idx >> 16;
    float w9[9];
#pragma unroll
    for (int t = 0; t < 9; ++t) w9[t] = w[co * 9 + t];
    float bv = bias[co];
    const float* ip = in + (size_t)b * 4096;
    float p[4][4];
#pragma unroll
    for (int r = 0; r < 4; ++r) {
        int gy = 2 * y - 1 + r;
#pragma unroll
        for (int c = 0; c < 4; ++c) {
            int gx = 2 * x - 1 + c;
            float v = 0.f;
            if ((unsigned)gy < 64u && (unsigned)gx < 64u) v = ip[gy * 64 + gx];
            p[r][c] = v;
        }
    }
    float s4 = 0.f;
#pragma unroll
    for (int dy = 0; dy < 2; ++dy)
#pragma unroll
        for (int dx = 0; dx < 2; ++dx) {
            float a = bv;
#pragma unroll
            for (int ky = 0; ky < 3; ++ky)
#pragma unroll
                for (int kx = 0; kx < 3; ++kx)
                    a = fmaf(w9[ky * 3 + kx], p[dy + ky][dx + kx], a);
            s4 += fmaxf(a, 0.f);
        }
    unsigned short h, l;
    bf16split(s4 * 0.25f, h, l);
    size_t a = ((size_t)(b * 34 + y + 1) * 34 + x + 1) * 64 + co;
    ohi[a] = h; olo[a] = l;
}

// ---- LDS-staged MFMA implicit-GEMM 64->64 3x3 SAME conv + relu (body) ----
// A tile in LDS (XOR-swizzled); B (t,ch)-slice in LDS double-buffer (8KB),
// staged by one cooperative 512x16B load per k-iter.
template <int UP, int H, bool NHWC_OUT>
__device__ __forceinline__ void conv_mfma_body(
    const unsigned short* __restrict__ ahi, const unsigned short* __restrict__ alo,
    const unsigned short* __restrict__ whiP, const unsigned short* __restrict__ wloP,
    const float* __restrict__ bias,
    float* __restrict__ outf, unsigned short* __restrict__ ohi,
    unsigned short* __restrict__ olo)
{
    constexpr int SRC   = H >> UP;
    constexpr int PITCH = SRC + 2;
    constexpr int TPR   = H / 16;
    constexpr int W     = UP ? 10 : 18;    // src-region width incl halo
    constexpr int NPX   = W * W;

    int b  = blockIdx.x / (TPR * TPR);
    int tt = blockIdx.x % (TPR * TPR);
    int y0 = (tt / TPR) * 16, x0 = (tt % TPR) * 16;
    const int tid = threadIdx.x;
    const int wv = tid >> 6, lane = tid & 63;
    const int lc = lane & 15, kg = lane >> 4;

    __shared__ unsigned short sAhi[NPX * 64];
    __shared__ unsigned short sAlo[NPX * 64];
    __shared__ unsigned short sW[2][4096];          // [buf][hi 2048 | lo 2048]

    const int r0 = ((y0 - 1) >> UP) + 1;   // padded-coord region start
    const int c0 = ((x0 - 1) >> UP) + 1;

    // stage A: coalesced 16B chunks, XOR-swizzled destination
    for (int c = tid; c < NPX * 8; c += 512) {
        int pix = c >> 3, sub = c & 7;
        int py = pix / W, px = pix - py * W;
        size_t g = ((size_t)(b * PITCH + r0 + py) * PITCH + (c0 + px)) * 64 + sub * 8;
        int l = (pix * 64 + sub * 8) ^ ((pix & 7) << 3);
        *(short8*)&sAhi[l] = *(const short8*)&ahi[g];
        *(short8*)&sAlo[l] = *(const short8*)&alo[g];
    }
    // stage W slice k=0
    {
        int c = tid & 255;
        if (tid < 256) *(short8*)&sW[0][c * 8]        = *(const short8*)&whiP[c * 8];
        else           *(short8*)&sW[0][2048 + c * 8] = *(const short8*)&wloP[c * 8];
    }
    __syncthreads();

    // per-lane local pixel coords
    int lxv[3], lyv[4];
#pragma unroll
    for (int kx = 0; kx < 3; ++kx)
        lxv[kx] = (((x0 + lc + kx - 1) >> UP) + 1) - c0;
#pragma unroll
    for (int r = 0; r < 4; ++r)
        lyv[r] = (((y0 + 2 * wv + r - 1) >> UP) + 1) - r0;

    f32x4 acc[2][4];
#pragma unroll
    for (int m = 0; m < 2; ++m)
#pragma unroll
        for (int n = 0; n < 4; ++n) acc[m][n] = f32x4{0.f, 0.f, 0.f, 0.f};

#pragma unroll
    for (int k = 0; k < 18; ++k) {                  // k = t*2 + ch
        // prefetch next W slice into the other buffer (hazard-safe: the
        // end-of-iter barrier of k-1 ordered all reads of buf[(k+1)&1])
        if (k + 1 < 18) {
            int slb = (k + 1) * 2048;
            int c = tid & 255;
            if (tid < 256) *(short8*)&sW[(k + 1) & 1][c * 8]        = *(const short8*)&whiP[slb + c * 8];
            else           *(short8*)&sW[(k + 1) & 1][2048 + c * 8] = *(const short8*)&wloP[slb + c * 8];
        }
        const int t = k >> 1, ch = k & 1;
        const int ky = t / 3, kx = t - ky * 3;
        int p0 = lyv[ky]     * W + lxv[kx];
        int p1 = lyv[ky + 1] * W + lxv[kx];
        int i0 = (p0 * 64 + ch * 32 + kg * 8) ^ ((p0 & 7) << 3);
        int i1 = (p1 * 64 + ch * 32 + kg * 8) ^ ((p1 & 7) << 3);
        short8 ah0 = *(const short8*)&sAhi[i0];
        short8 ah1 = *(const short8*)&sAhi[i1];
        short8 al0 = *(const short8*)&sAlo[i0];
        short8 al1 = *(const short8*)&sAlo[i1];
        const unsigned short* wb = &sW[k & 1][0];
#pragma unroll
        for (int n = 0; n < 4; ++n) {
            short8 bh = *(const short8*)&wb[(n * 64 + lane) * 8];
            short8 bl = *(const short8*)&wb[2048 + (n * 64 + lane) * 8];
            acc[0][n] = __builtin_amdgcn_mfma_f32_16x16x32_bf16(ah0, bh, acc[0][n], 0, 0, 0);
            acc[0][n] = __builtin_amdgcn_mfma_f32_16x16x32_bf16(ah0, bl, acc[0][n], 0, 0, 0);
            acc[0][n] = __builtin_amdgcn_mfma_f32_16x16x32_bf16(al0, bh, acc[0][n], 0, 0, 0);
            acc[1][n] = __builtin_amdgcn_mfma_f32_16x16x32_bf16(ah1, bh, acc[1][n], 0, 0, 0);
            acc[1][n] = __builtin_amdgcn_mfma_f32_16x16x32_bf16(ah1, bl, acc[1][n], 0, 0, 0);
            acc[1][n] = __builtin_amdgcn_mfma_f32_16x16x32_bf16(al1, bh, acc[1][n], 0, 0, 0);
        }
        __syncthreads();
    }

    // epilogue: D col(lane&15)=co frag idx, row(kg*4+reg)=pixel-x (verified r4)
    if (NHWC_OUT) {
        const int opitch = H + 2;
#pragma unroll
        for (int n = 0; n < 4; ++n) {
            int co = n * 16 + lc;
            float bv = bias[co];
#pragma unroll
            for (int m = 0; m < 2; ++m) {
                int row = y0 + 2 * wv + m, cb = x0 + kg * 4;
                f32x4 v = acc[m][n];
#pragma unroll
                for (int j = 0; j < 4; ++j) {
                    float val = fmaxf(v[j] + bv, 0.f);
                    unsigned short h, l;
                    bf16split(val, h, l);
                    size_t a = ((size_t)(b * opitch + row + 1) * opitch + cb + j + 1) * 64 + co;
                    ohi[a] = h; olo[a] = l;
                }
            }
        }
    } else {
#pragma unroll
        for (int n = 0; n < 4; ++n) {
            int co = n * 16 + lc;
            float bv = bias[co];
#pragma unroll
            for (int m = 0; m < 2; ++m) {
                int row = y0 + 2 * wv + m, cb = x0 + kg * 4;
                f32x4 v = acc[m][n], res;
                res.x = fmaxf(v.x + bv, 0.f);
                res.y = fmaxf(v.y + bv, 0.f);
                res.z = fmaxf(v.z + bv, 0.f);
                res.w = fmaxf(v.w + bv, 0.f);
                *(f32x4*)&outf[((size_t)(b * 64 + co) * H + row) * H + cb] = res;
            }
        }
    }
}

// distinct names per layer -> per-layer rocprof rows
__global__ __launch_bounds__(512) void conv1_mfma_kernel(
    const unsigned short* __restrict__ ahi, const unsigned short* __restrict__ alo,
    const unsigned short* __restrict__ whiP, const unsigned short* __restrict__ wloP,
    const float* __restrict__ bias, float* __restrict__ outf)
{ conv_mfma_body<0, 32, false>(ahi, alo, whiP, wloP, bias, outf, nullptr, nullptr); }

__global__ __launch_bounds__(512) void conv3_mfma_kernel(
    const unsigned short* __restrict__ ahi, const unsigned short* __restrict__ alo,
    const unsigned short* __restrict__ whiP, const unsigned short* __restrict__ wloP,
    const float* __restrict__ bias,
    unsigned short* __restrict__ ohi, unsigned short* __restrict__ olo)
{ conv_mfma_body<1, 32, true>(ahi, alo, whiP, wloP, bias, nullptr, ohi, olo); }

__global__ __launch_bounds__(512) void conv4_mfma_kernel(
    const unsigned short* __restrict__ ahi, const unsigned short* __restrict__ alo,
    const unsigned short* __restrict__ whiP, const unsigned short* __restrict__ wloP,
    const float* __restrict__ bias, float* __restrict__ outf)
{ conv_mfma_body<1, 64, false>(ahi, alo, whiP, wloP, bias, outf, nullptr, nullptr); }

// ---- avgpool2: (64,64,32,32) -> (64,64,16,16) NCHW f32 ----
__global__ void pool_kernel(const float* __restrict__ in, float* __restrict__ out, int Ho)
{
    int idx = blockIdx.x * 256 + threadIdx.x;
    int n = 64 * 64 * Ho * Ho;
    if (idx >= n) return;
    int x = idx % Ho; int y = (idx / Ho) % Ho; int p = idx / (Ho * Ho);
    int Hi = 2 * Ho;
    const float* ip = in + (size_t)p * Hi * Hi;
    float s = ip[(2 * y) * Hi + 2 * x] + ip[(2 * y) * Hi + 2 * x + 1]
            + ip[(2 * y + 1) * Hi + 2 * x] + ip[(2 * y + 1) * Hi + 2 * x + 1];
    out[idx] = s * 0.25f;
}

// ---- enc conv: 64->1, 16x16, relu -> x (64,256) ----
__global__ __launch_bounds__(256) void enc_kernel(
    const float* __restrict__ in, const float* __restrict__ w,
    const float* __restrict__ bias, float* __restrict__ xout)
{
    int b = blockIdx.x; int tid = threadIdx.x;
    int y = tid >> 4, x = tid & 15;
    __shared__ float sE[8192];
    double acc = 0.0;
    for (int ch = 0; ch < 2; ++ch) {
        __syncthreads();
        for (int k = tid; k < 8192; k += 256) sE[k] = in[(size_t)b * 16384 + ch * 8192 + k];
        __syncthreads();
        for (int cip = 0; cip < 32; ++cip) {
            int ci = ch * 32 + cip;
#pragma unroll
            for (int ky = 0; ky < 3; ++ky) {
                int gy = y + ky - 1;
                if ((unsigned)gy >= 16u) continue;
#pragma unroll
                for (int kx = 0; kx < 3; ++kx) {
                    int gx = x + kx - 1;
                    if ((unsigned)gx >= 16u) continue;
                    acc = fma((double)w[ci * 9 + ky * 3 + kx],
                              (double)sE[cip * 256 + gy * 16 + gx], acc);
                }
            }
        }
    }
    float v = (float)(acc + (double)bias[0]);
    xout[b * 256 + tid] = fmaxf(v, 0.f);
}

// ---- LSTM (zero state): h = sig(zo)*tanh(sig(zi)*tanh(zg)) ----
__global__ __launch_bounds__(256) void lstm_kernel(
    const float* __restrict__ x, const float* __restrict__ wx,
    const float* __restrict__ bl, float* __restrict__ h)
{
    int b = blockIdx.x, j = threadIdx.x;
    __shared__ float sx[256];
    sx[j] = x[b * 256 + j];
    __syncthreads();
    double zi = 0, zg = 0, zo = 0;
    for (int d = 0; d < 256; ++d) {
        double xv = (double)sx[d];
        const float* row = wx + (size_t)d * 1024;
        zi = fma(xv, (double)row[j], zi);
        zg = fma(xv, (double)row[512 + j], zg);
        zo = fma(xv, (double)row[768 + j], zo);
    }
    float zif = (float)(zi + (double)bl[j]);
    float zgf = (float)(zg + (double)bl[512 + j]);
    float zof = (float)(zo + (double)bl[768 + j]);
    double c = (1.0 / (1.0 + exp(-(double)zif))) * tanh((double)zgf);
    float cf = (float)c;
    double hh = (1.0 / (1.0 + exp(-(double)zof))) * tanh((double)cf);
    h[b * 256 + j] = (float)hh;
}

// ---- rowsums of w_out reads-block ----
__global__ void rowsum_kernel(const float* __restrict__ w_out, double* __restrict__ rs)
{
    int r = blockIdx.x, m = threadIdx.x;
    double s = 0;
    for (int d = 0; d < 256; ++d) s += (double)w_out[(size_t)(256 + r * 256 + d) * 256 + m];
    rs[r * 256 + m] = s;
}

// ---- read-head scalar rv[b,r] ----
__global__ __launch_bounds__(256) void gamma_kernel(
    const float* __restrict__ h, const float* __restrict__ w_param,
    const float* __restrict__ b_param, double* __restrict__ rv)
{
    int b = blockIdx.x, t = threadIdx.x;
    __shared__ double sp[3][256];
    float hv = h[b * 256 + t];
#pragma unroll
    for (int r = 0; r < 3; ++r)
        sp[r][t] = (double)hv * (double)w_param[(size_t)t * 3108 + r * 262 + 261];
    __syncthreads();
    if (t < 3) {
        double s = 0;
        for (int d = 0; d < 256; ++d) s += sp[t][d];
        float pf = (float)(s + (double)b_param[t * 262 + 261]);
        pf = fminf(fmaxf(pf, -20.f), 20.f);
        double gamma = log1p(exp((double)pf)) + 1.0;
        double q = pow(0.015625 + 1e-16, gamma);
        double wv = q / (64.0 * q + 1e-8);
        rv[b * 3 + t] = wv * 64.0 * 1e-6;
    }
}

// ---- ntm out: clip(h@w_out[:256] + b_out + sum_r rv_r*rs_r, +-20) ----
__global__ __launch_bounds__(256) void ntmout_kernel(
    const float* __restrict__ h, const float* __restrict__ w_out,
    const float* __restrict__ b_out, const double* __restrict__ rv,
    const double* __restrict__ rs, float* __restrict__ out)
{
    int b = blockIdx.x, m = threadIdx.x;
    __shared__ float sh[256];
    __shared__ double srv[3];
    sh[m] = h[b * 256 + m];
    if (m < 3) srv[m] = rv[b * 3 + m];
    __syncthreads();
    double acc = 0;
    for (int d = 0; d < 256; ++d)
        acc = fma((double)sh[d], (double)w_out[(size_t)d * 256 + m], acc);
    acc += (double)b_out[m];
#pragma unroll
    for (int r = 0; r < 3; ++r) acc += srv[r] * rs[r * 256 + m];
    acc = fmin(fmax(acc, -20.0), 20.0);
    out[b * 256 + m] = (float)acc;
}

// ---- conv2: 1->64 3x3 SAME + relu, ntm (64,16,16) -> A3 NHWC hi/lo ----
__global__ __launch_bounds__(256) void conv2_kernel(
    const float* __restrict__ in, const float* __restrict__ w,
    const float* __restrict__ bias,
    unsigned short* __restrict__ ohi, unsigned short* __restrict__ olo)
{
    int idx = blockIdx.x * 256 + threadIdx.x;      // 64*16*16*64 = 1,048,576
    int co = idx & 63, x = (idx >> 6) & 15, y = (idx >> 10) & 15, b = idx >> 14;
    float acc = bias[co];
    const float* ip = in + (size_t)b * 256;
#pragma unroll
    for (int ky = 0; ky < 3; ++ky) {
        int gy = y + ky - 1;
        if ((unsigned)gy >= 16u) continue;
#pragma unroll
        for (int kx = 0; kx < 3; ++kx) {
            int gx = x + kx - 1;
            if ((unsigned)gx >= 16u) continue;
            acc = fmaf(w[co * 9 + ky * 3 + kx], ip[gy * 16 + gx], acc);
        }
    }
    unsigned short h, l;
    bf16split(fmaxf(acc, 0.f), h, l);
    size_t a = ((size_t)(b * 18 + y + 1) * 18 + x + 1) * 64 + co;
    ohi[a] = h; olo[a] = l;
}

extern "C" void kernel_launch(void* const* d_in, const int* in_sizes, int n_in,
                              void* d_out, int out_size, void* d_ws, size_t ws_size,
                              hipStream_t stream)
{
    const float* inputs   = (const float*)d_in[0];
    const float* w_conv0  = (const float*)d_in[1];
    const float* b_conv0  = (const float*)d_in[2];
    const float* w_conv1  = (const float*)d_in[3];
    const float* b_conv1  = (const float*)d_in[4];
    const float* w_enc    = (const float*)d_in[5];
    const float* b_enc    = (const float*)d_in[6];
    const float* w_conv2  = (const float*)d_in[7];
    const float* b_conv2  = (const float*)d_in[8];
    const float* w_conv3  = (const float*)d_in[9];
    const float* b_conv3  = (const float*)d_in[10];
    const float* w_conv4  = (const float*)d_in[11];
    const float* b_conv4  = (const float*)d_in[12];
    const float* w_lstm_x = (const float*)d_in[13];
    // d_in[14] = w_lstm_h : dead (h0 == 0)
    const float* b_lstm   = (const float*)d_in[15];
    const float* w_param  = (const float*)d_in[16];
    const float* b_param  = (const float*)d_in[17];
    const float* w_out_   = (const float*)d_in[18];
    const float* b_out_   = (const float*)d_in[19];

    char* ws = (char*)d_ws;
    unsigned short* a1h = (unsigned short*)(ws + OFF_A1H);
    unsigned short* a1l = (unsigned short*)(ws + OFF_A1L);
    float*  t1  = (float*)(ws + OFF_T1);
    float*  t2  = (float*)(ws + OFF_T2);
    unsigned short* a3h = (unsigned short*)(ws + OFF_A3H);
    unsigned short* a3l = (unsigned short*)(ws + OFF_A3L);
    // A4 reuses A1 (same shape/pitch; a1 dead after conv1; ring stays zero)
    unsigned short* a4h = a1h;
    unsigned short* a4l = a1l;
    unsigned short* whi1 = (unsigned short*)(ws + OFF_W1); unsigned short* wlo1 = whi1 + 36864;
    unsigned short* whi3 = (unsigned short*)(ws + OFF_W3); unsigned short* wlo3 = whi3 + 36864;
    unsigned short* whi4 = (unsigned short*)(ws + OFF_W4); unsigned short* wlo4 = whi4 + 36864;
    float*  xE  = (float*)(ws + OFF_XE);
    float*  h   = (float*)(ws + OFF_H);
    double* rv  = (double*)(ws + OFF_RV);
    double* rs  = (double*)(ws + OFF_RS);
    float*  ntm = (float*)(ws + OFF_N);

    wprep_kernel<<<144, 256, 0, stream>>>(w_conv1, whi1, wlo1);
    wprep_kernel<<<144, 256, 0, stream>>>(w_conv3, whi3, wlo3);
    wprep_kernel<<<144, 256, 0, stream>>>(w_conv4, whi4, wlo4);

    halo_zero_kernel<<<2112, 256, 0, stream>>>(a1h, a1l, 32);   // also serves conv4 input
    halo_zero_kernel<<<1088, 256, 0, stream>>>(a3h, a3l, 16);

    conv0_pool_kernel<<<16384, 256, 0, stream>>>(inputs, w_conv0, b_conv0, a1h, a1l);
    conv1_mfma_kernel<<<256, 512, 0, stream>>>(a1h, a1l, whi1, wlo1, b_conv1, t1);
    pool_kernel<<<4096, 256, 0, stream>>>(t1, t2, 16);
    enc_kernel<<<64, 256, 0, stream>>>(t2, w_enc, b_enc, xE);

    lstm_kernel<<<64, 256, 0, stream>>>(xE, w_lstm_x, b_lstm, h);
    rowsum_kernel<<<3, 256, 0, stream>>>(w_out_, rs);
    gamma_kernel<<<64, 256, 0, stream>>>(h, w_param, b_param, rv);
    ntmout_kernel<<<64, 256, 0, stream>>>(h, w_out_, b_out_, rv, rs, ntm);

    conv2_kernel<<<4096, 256, 0, stream>>>(ntm, w_conv2, b_conv2, a3h, a3l);
    conv3_mfma_kernel<<<256, 512, 0, stream>>>(a3h, a3l, whi3, wlo3, b_conv3, a4h, a4l);
    conv4_mfma_kernel<<<1024, 512, 0, stream>>>(a4h, a4l, whi4, wlo4, b_conv4, (float*)d_out);
}